// Round 2
// baseline (1714.274 us; speedup 1.0000x reference)
//
#include <hip/hip_runtime.h>
#include <hip/hip_bf16.h>

// Problem constants (fixed by setup_inputs)
#define TDIM 4096
#define BDIM 4
#define DDIM 1024
#define HDIM 16
#define HD   64
#define MDIM (TDIM * BDIM)      // 16384 rows (t,b)
#define S3D  (3 * DDIM)         // 3072, qkv row width
#define RS   ((size_t)(BDIM * S3D))  // 12288 floats between consecutive t in qkv

// ---------------------------------------------------------------------------
// GEMM: C[m][n] = A[m][:] . B[n][:] + bias[n]   (A rows stride lda, B rows
// stride K contiguous). Batched via blockIdx.z with batchA/batchB/batchC
// element strides. 128x128 tile, BK=16, 256 threads, 8x8 per thread,
// reg-prefetch next K-slab.
// ---------------------------------------------------------------------------
#define GBM 128
#define GBN 128
#define GBK 16
#define LDT 132   // padded LDS row stride

__global__ __launch_bounds__(256, 2)
void gemm_nt(const float* __restrict__ A, const float* __restrict__ Bm,
             const float* __restrict__ bias, float* __restrict__ C,
             int M, int N, int K, int lda, int ldc,
             size_t batchA, size_t batchB, size_t batchC)
{
  __shared__ float As[GBK][LDT];
  __shared__ float Bs[GBK][LDT];
  const float* Ab = A  + (size_t)blockIdx.z * batchA;
  const float* Bb = Bm + (size_t)blockIdx.z * batchB;
  float*       Cb = C  + (size_t)blockIdx.z * batchC;
  const int tid = threadIdx.x;
  const int m0 = blockIdx.y * GBM;
  const int n0 = blockIdx.x * GBN;
  const int ty = tid >> 4;      // 0..15 -> rows ty*8..+8
  const int tx = tid & 15;      // 0..15 -> cols tx*4..+4 and 64+tx*4..+4
  const int r0 = tid >> 2;      // 0..63 staging row
  const int kq = tid & 3;       // float4 slot within BK

  float acc[8][8];
#pragma unroll
  for (int i = 0; i < 8; ++i)
#pragma unroll
    for (int j = 0; j < 8; ++j) acc[i][j] = 0.f;

  const float* Ap0 = Ab + (size_t)(m0 + r0) * lda + kq * 4;
  const float* Ap1 = Ap0 + (size_t)64 * lda;
  const float* Bp0 = Bb + (size_t)(n0 + r0) * K + kq * 4;
  const float* Bp1 = Bp0 + (size_t)64 * K;

  // preload first slab into regs
  float4 a0 = *(const float4*)(Ap0);
  float4 a1 = *(const float4*)(Ap1);
  float4 b0 = *(const float4*)(Bp0);
  float4 b1 = *(const float4*)(Bp1);

  for (int k0 = 0; k0 < K; k0 += GBK) {
    __syncthreads();  // previous iter's readers done
    As[kq*4+0][r0]    = a0.x; As[kq*4+1][r0]    = a0.y; As[kq*4+2][r0]    = a0.z; As[kq*4+3][r0]    = a0.w;
    As[kq*4+0][r0+64] = a1.x; As[kq*4+1][r0+64] = a1.y; As[kq*4+2][r0+64] = a1.z; As[kq*4+3][r0+64] = a1.w;
    Bs[kq*4+0][r0]    = b0.x; Bs[kq*4+1][r0]    = b0.y; Bs[kq*4+2][r0]    = b0.z; Bs[kq*4+3][r0]    = b0.w;
    Bs[kq*4+0][r0+64] = b1.x; Bs[kq*4+1][r0+64] = b1.y; Bs[kq*4+2][r0+64] = b1.z; Bs[kq*4+3][r0+64] = b1.w;
    __syncthreads();
    if (k0 + GBK < K) {  // prefetch next slab; loads overlap compute below
      a0 = *(const float4*)(Ap0 + k0 + GBK);
      a1 = *(const float4*)(Ap1 + k0 + GBK);
      b0 = *(const float4*)(Bp0 + k0 + GBK);
      b1 = *(const float4*)(Bp1 + k0 + GBK);
    }
#pragma unroll
    for (int k = 0; k < GBK; ++k) {
      const float4 af0 = *(const float4*)&As[k][ty*8];
      const float4 af1 = *(const float4*)&As[k][ty*8+4];
      const float4 bf0 = *(const float4*)&Bs[k][tx*4];
      const float4 bf1 = *(const float4*)&Bs[k][64 + tx*4];
      const float av[8] = {af0.x, af0.y, af0.z, af0.w, af1.x, af1.y, af1.z, af1.w};
      const float bv[8] = {bf0.x, bf0.y, bf0.z, bf0.w, bf1.x, bf1.y, bf1.z, bf1.w};
#pragma unroll
      for (int i = 0; i < 8; ++i)
#pragma unroll
        for (int j = 0; j < 8; ++j)
          acc[i][j] = fmaf(av[i], bv[j], acc[i][j]);
    }
  }

  const float4 bias0 = *(const float4*)&bias[n0 + tx*4];
  const float4 bias1 = *(const float4*)&bias[n0 + 64 + tx*4];
#pragma unroll
  for (int i = 0; i < 8; ++i) {
    const size_t row = (size_t)(m0 + ty*8 + i);
    float4 o0, o1;
    o0.x = acc[i][0] + bias0.x; o0.y = acc[i][1] + bias0.y;
    o0.z = acc[i][2] + bias0.z; o0.w = acc[i][3] + bias0.w;
    o1.x = acc[i][4] + bias1.x; o1.y = acc[i][5] + bias1.y;
    o1.z = acc[i][6] + bias1.z; o1.w = acc[i][7] + bias1.w;
    *(float4*)&Cb[row * ldc + n0 + tx*4]      = o0;
    *(float4*)&Cb[row * ldc + n0 + 64 + tx*4] = o1;
  }
}

// ---------------------------------------------------------------------------
// Correlation partials: grid (64 bh, 16 seg), 1 wave per block.
// Partial c[64][64] = sum_t q[t][d]*k[t][e] over a 256-t segment, plus
// partial sums sq, sk, sq2, sk2. Record: 4096 c + 256 sums = 4352 floats.
// ---------------------------------------------------------------------------
__global__ __launch_bounds__(64)
void corr_partial(const float* __restrict__ qkv, float* __restrict__ P)
{
  __shared__ float qs[32][64];
  __shared__ float ks[32][64];
  const int bh  = blockIdx.x;
  const int seg = blockIdx.y;
  const int b = bh >> 4;
  const int h = bh & 15;
  const int lane = threadIdx.x;
  const float* qb = qkv + (size_t)b * S3D + h * HD;   // + t*RS
  const float* kb = qb + DDIM;
  const int ty = lane >> 3;   // 0..7 -> d rows ty*8..+8
  const int tx = lane & 7;    // 0..7 -> e cols tx*8..+8
  const int rr = lane >> 4;   // staging row base 0..3
  const int cq = lane & 15;   // staging float4 col

  float acc[8][8];
#pragma unroll
  for (int i = 0; i < 8; ++i)
#pragma unroll
    for (int j = 0; j < 8; ++j) acc[i][j] = 0.f;
  float sQ[4]  = {0,0,0,0}, sK[4]  = {0,0,0,0};
  float sQ2[4] = {0,0,0,0}, sK2[4] = {0,0,0,0};

  for (int c = 0; c < 8; ++c) {       // 8 chunks of 32 t
    const int tbase = seg * 256 + c * 32;
    float4 qv[8], kv[8];
#pragma unroll
    for (int i = 0; i < 8; ++i) {
      const size_t g = (size_t)(tbase + rr + i*4) * RS + cq * 4;
      qv[i] = *(const float4*)&qb[g];
      kv[i] = *(const float4*)&kb[g];
    }
    __syncthreads();
#pragma unroll
    for (int i = 0; i < 8; ++i) {
      const int row = rr + i*4;
      *(float4*)&qs[row][cq*4] = qv[i];
      *(float4*)&ks[row][cq*4] = kv[i];
      sQ[0] += qv[i].x; sQ[1] += qv[i].y; sQ[2] += qv[i].z; sQ[3] += qv[i].w;
      sK[0] += kv[i].x; sK[1] += kv[i].y; sK[2] += kv[i].z; sK[3] += kv[i].w;
      sQ2[0] = fmaf(qv[i].x, qv[i].x, sQ2[0]); sQ2[1] = fmaf(qv[i].y, qv[i].y, sQ2[1]);
      sQ2[2] = fmaf(qv[i].z, qv[i].z, sQ2[2]); sQ2[3] = fmaf(qv[i].w, qv[i].w, sQ2[3]);
      sK2[0] = fmaf(kv[i].x, kv[i].x, sK2[0]); sK2[1] = fmaf(kv[i].y, kv[i].y, sK2[1]);
      sK2[2] = fmaf(kv[i].z, kv[i].z, sK2[2]); sK2[3] = fmaf(kv[i].w, kv[i].w, sK2[3]);
    }
    __syncthreads();
#pragma unroll 8
    for (int t = 0; t < 32; ++t) {
      const float4 qa  = *(const float4*)&qs[t][ty*8];
      const float4 qb4 = *(const float4*)&qs[t][ty*8+4];
      const float4 ka  = *(const float4*)&ks[t][tx*8];
      const float4 kb4 = *(const float4*)&ks[t][tx*8+4];
      const float av[8] = {qa.x, qa.y, qa.z, qa.w, qb4.x, qb4.y, qb4.z, qb4.w};
      const float bv[8] = {ka.x, ka.y, ka.z, ka.w, kb4.x, kb4.y, kb4.z, kb4.w};
#pragma unroll
      for (int i = 0; i < 8; ++i)
#pragma unroll
        for (int j = 0; j < 8; ++j)
          acc[i][j] = fmaf(av[i], bv[j], acc[i][j]);
    }
  }

  // reduce sums across lanes {cq, cq+16, cq+32, cq+48}
#pragma unroll
  for (int j = 0; j < 4; ++j) {
    sQ[j]  += __shfl_xor(sQ[j], 16, 64);  sQ[j]  += __shfl_xor(sQ[j], 32, 64);
    sK[j]  += __shfl_xor(sK[j], 16, 64);  sK[j]  += __shfl_xor(sK[j], 32, 64);
    sQ2[j] += __shfl_xor(sQ2[j], 16, 64); sQ2[j] += __shfl_xor(sQ2[j], 32, 64);
    sK2[j] += __shfl_xor(sK2[j], 16, 64); sK2[j] += __shfl_xor(sK2[j], 32, 64);
  }

  float* Pb = P + (size_t)(bh * 16 + seg) * 4352;
#pragma unroll
  for (int i = 0; i < 8; ++i) {
    const int row = ty*8 + i;
    float4 o0, o1;
    o0.x = acc[i][0]; o0.y = acc[i][1]; o0.z = acc[i][2]; o0.w = acc[i][3];
    o1.x = acc[i][4]; o1.y = acc[i][5]; o1.z = acc[i][6]; o1.w = acc[i][7];
    *(float4*)&Pb[row*64 + tx*8]     = o0;
    *(float4*)&Pb[row*64 + tx*8 + 4] = o1;
  }
  if (lane < 16) {
    float4 q4; q4.x = sQ[0];  q4.y = sQ[1];  q4.z = sQ[2];  q4.w = sQ[3];
    float4 k4; k4.x = sK[0];  k4.y = sK[1];  k4.z = sK[2];  k4.w = sK[3];
    float4 q2; q2.x = sQ2[0]; q2.y = sQ2[1]; q2.z = sQ2[2]; q2.w = sQ2[3];
    float4 k2; k2.x = sK2[0]; k2.y = sK2[1]; k2.z = sK2[2]; k2.w = sK2[3];
    *(float4*)&Pb[4096 + lane*4] = q4;
    *(float4*)&Pb[4160 + lane*4] = k4;
    *(float4*)&Pb[4224 + lane*4] = q2;
    *(float4*)&Pb[4288 + lane*4] = k2;
  }
}

// ---------------------------------------------------------------------------
// Finalize: sum 16 segment partials; corr = clip((c - SqSk/T) /
// sqrt((Sq2-Sq^2/T)(Sk2-Sk^2/T)), -1, 1).  grid 64 (bh), 256 threads.
// ---------------------------------------------------------------------------
__global__ __launch_bounds__(256)
void corr_finalize(const float* __restrict__ P, float* __restrict__ corr)
{
  __shared__ float fin[4][64];   // sq, sk, sq2, sk2
  const int bh = blockIdx.x;
  const int tid = threadIdx.x;
  const float* Pb = P + (size_t)bh * 16 * 4352;

  float s = 0.f;
  for (int seg = 0; seg < 16; ++seg) s += Pb[(size_t)seg*4352 + 4096 + tid];
  fin[tid >> 6][tid & 63] = s;

  float cacc[16];
#pragma unroll
  for (int i = 0; i < 16; ++i) cacc[i] = 0.f;
  for (int seg = 0; seg < 16; ++seg) {
#pragma unroll
    for (int i = 0; i < 16; ++i)
      cacc[i] += Pb[(size_t)seg*4352 + tid + i*256];
  }
  __syncthreads();

  const float invT = 1.0f / (float)TDIM;
#pragma unroll
  for (int i = 0; i < 16; ++i) {
    const int f = tid + i*256;
    const int d = f >> 6, e = f & 63;
    const float sq = fin[0][d], sk = fin[1][e];
    const float sq2 = fin[2][d], sk2 = fin[3][e];
    const float cc = cacc[i] - sq * sk * invT;
    const float sx = sq2 - sq * sq * invT;
    const float sy = sk2 - sk * sk * invT;
    float v = cc / sqrtf(sx * sy);
    v = fminf(1.f, fmaxf(-1.f, v));
    corr[(size_t)bh * 4096 + f] = v;
  }
}

// ---------------------------------------------------------------------------
// Weff_b[n][h*64+d] = sum_e corr[b,h][d][e] * Wout[n][h*64+e]
// Folding corr into Wout lets the final GEMM read v directly (no attn buffer).
// grid (64 bh, 8 n-chunks of 128), 256 threads.
// ---------------------------------------------------------------------------
__global__ __launch_bounds__(256)
void weff_kernel(const float* __restrict__ corr, const float* __restrict__ Wout,
                 float* __restrict__ Weff)
{
  __shared__ float cs[64][64];    // corr[d][e]
  __shared__ float ws[128][64];   // Wout[n0+i][h*64+e]
  const int bh = blockIdx.x;
  const int b = bh >> 4, h = bh & 15;
  const int n0 = blockIdx.y * 128;
  const int tid = threadIdx.x;

  const float* cb = corr + (size_t)bh * 4096;
  float4* csv = (float4*)&cs[0][0];
#pragma unroll
  for (int i = 0; i < 4; ++i)
    csv[tid + 256*i] = ((const float4*)cb)[tid + 256*i];

  const int wr = tid >> 1, wh = (tid & 1) * 32;
  const float* wrow = Wout + (size_t)(n0 + wr) * DDIM + h * HD + wh;
#pragma unroll
  for (int i = 0; i < 8; ++i)
    *(float4*)&ws[wr][wh + i*4] = *(const float4*)&wrow[i*4];
  __syncthreads();

  const int ni = (tid >> 3) * 4;   // 4 n-rows
  const int di = (tid & 7) * 8;    // 8 d-cols
  float acc[4][8];
#pragma unroll
  for (int i = 0; i < 4; ++i)
#pragma unroll
    for (int j = 0; j < 8; ++j) acc[i][j] = 0.f;

  for (int e = 0; e < 64; ++e) {
    float wv[4], cv[8];
#pragma unroll
    for (int i = 0; i < 4; ++i) wv[i] = ws[ni + i][e];
#pragma unroll
    for (int j = 0; j < 8; ++j) cv[j] = cs[di + j][e];
#pragma unroll
    for (int i = 0; i < 4; ++i)
#pragma unroll
      for (int j = 0; j < 8; ++j)
        acc[i][j] = fmaf(wv[i], cv[j], acc[i][j]);
  }

  float* Wb = Weff + (size_t)b * DDIM * DDIM + h * HD;
#pragma unroll
  for (int i = 0; i < 4; ++i) {
    float4 o0, o1;
    o0.x = acc[i][0]; o0.y = acc[i][1]; o0.z = acc[i][2]; o0.w = acc[i][3];
    o1.x = acc[i][4]; o1.y = acc[i][5]; o1.z = acc[i][6]; o1.w = acc[i][7];
    *(float4*)&Wb[(size_t)(n0 + ni + i) * DDIM + di]     = o0;
    *(float4*)&Wb[(size_t)(n0 + ni + i) * DDIM + di + 4] = o1;
  }
}

// ---------------------------------------------------------------------------
extern "C" void kernel_launch(void* const* d_in, const int* in_sizes, int n_in,
                              void* d_out, int out_size, void* d_ws, size_t ws_size,
                              hipStream_t stream)
{
  (void)in_sizes; (void)n_in; (void)out_size; (void)ws_size;
  const float* x    = (const float*)d_in[0];
  const float* Wqkv = (const float*)d_in[1];
  const float* bqkv = (const float*)d_in[2];
  const float* Wout = (const float*)d_in[3];
  const float* bout = (const float*)d_in[4];
  float* out = (float*)d_out;

  // ws layout (floats): qkv 50,331,648 | corr 262,144 | P 4,456,448 | Weff 4,194,304
  // total = 59,244,544 floats = 226.0 MiB  (previous layout was 257 MiB -> fault)
  float* qkv  = (float*)d_ws;
  float* corr = qkv  + (size_t)MDIM * S3D;
  float* P    = corr + (size_t)64 * 64 * 64;
  float* Weff = P    + (size_t)64 * 16 * 4352;

  // 1) qkv = x @ Wqkv^T + bqkv
  gemm_nt<<<dim3(S3D / GBN, MDIM / GBM, 1), 256, 0, stream>>>(
      x, Wqkv, bqkv, qkv, MDIM, S3D, DDIM, DDIM, S3D, 0, 0, 0);
  // 2) correlation partials over T segments
  corr_partial<<<dim3(64, 16), 64, 0, stream>>>(qkv, P);
  // 3) finalize corr
  corr_finalize<<<dim3(64), 256, 0, stream>>>(P, corr);
  // 4) Weff_b = fold(corr_b, Wout)
  weff_kernel<<<dim3(64, 8), 256, 0, stream>>>(corr, Wout, Weff);
  // 5) out[t,b,:] = v[t,b,:] @ Weff_b^T + bout   (batched over b via grid.z)
  gemm_nt<<<dim3(DDIM / GBN, TDIM / GBM, BDIM), 256, 0, stream>>>(
      qkv + 2 * DDIM, Weff, bout, out,
      TDIM, DDIM, DDIM, (int)RS, BDIM * DDIM,
      (size_t)S3D, (size_t)DDIM * DDIM, (size_t)DDIM);
}

// Round 3
// 667.214 us; speedup vs baseline: 2.5693x; 2.5693x over previous
//
#include <hip/hip_runtime.h>
#include <hip/hip_bf16.h>

// Problem constants (fixed by setup_inputs)
#define TDIM 4096
#define BDIM 4
#define DDIM 1024
#define HDIM 16
#define HD   64
#define MDIM (TDIM * BDIM)      // 16384 rows (t,b)

typedef __attribute__((ext_vector_type(8))) short short8v;  // 8 bf16 bits = 4 VGPR
typedef __attribute__((ext_vector_type(4))) float f32x4;

__device__ __forceinline__ ushort f2bfu(float f) {
  union { __hip_bfloat16 h; ushort u; } c;
  c.h = __float2bfloat16(f);
  return c.u;
}
__device__ __forceinline__ float bfu2f(ushort u) {
  union { ushort u; __hip_bfloat16 h; } c;
  c.u = u;
  return __bfloat162float(c.h);
}

// async global->LDS, 16B per lane; LDS dest = wave-uniform base + lane*16
#define GLOAD16(gp, lp) __builtin_amdgcn_global_load_lds( \
    (const __attribute__((address_space(1))) void*)(gp),  \
    (__attribute__((address_space(3))) void*)(lp), 16, 0, 0)

// ---------------------------------------------------------------------------
// split fp32 -> bf16 hi/lo arrays (hi = bf16(x), lo = bf16(x - hi))
// ---------------------------------------------------------------------------
__global__ __launch_bounds__(256)
void split_f32(const float* __restrict__ in, ushort* __restrict__ hi,
               ushort* __restrict__ lo, int n4)
{
  int i = blockIdx.x * blockDim.x + threadIdx.x;
  const int stride = gridDim.x * blockDim.x;
  for (; i < n4; i += stride) {
    const float4 v = ((const float4*)in)[i];
    ushort4 h, l;
    h.x = f2bfu(v.x); l.x = f2bfu(v.x - bfu2f(h.x));
    h.y = f2bfu(v.y); l.y = f2bfu(v.y - bfu2f(h.y));
    h.z = f2bfu(v.z); l.z = f2bfu(v.z - bfu2f(h.z));
    h.w = f2bfu(v.w); l.w = f2bfu(v.w - bfu2f(h.w));
    ((ushort4*)hi)[i] = h;
    ((ushort4*)lo)[i] = l;
  }
}

// ---------------------------------------------------------------------------
// GEMM1: qkv = x @ Wqkv^T + bqkv via split-bf16 3-MFMA.
// A = x fp32 (reg-staged, split on the fly), B = pre-split Wh/Wl (gload_lds).
// Output: n<2048 -> fp32 QK[16384][2048]; n>=2048 -> bf16 hi/lo V[16384][1024].
// 128x128 tile, BK=32, 4 waves (2x2), each wave 4x4 frags of 16x16x32.
// LDS tiles XOR-swizzled with f(row)=row&3 on 16B slots (both sides, rule #21).
// ---------------------------------------------------------------------------
__global__ __launch_bounds__(256, 2)
void gemm1_mfma(const float* __restrict__ X, const ushort* __restrict__ Wh,
                const ushort* __restrict__ Wl, const float* __restrict__ bias,
                float* __restrict__ QK, ushort* __restrict__ Vh,
                ushort* __restrict__ Vl)
{
  __shared__ ushort sAh[128][32], sAl[128][32], sBh[128][32], sBl[128][32];
  const int tid = threadIdx.x;
  const int lane = tid & 63, wid = tid >> 6;
  const int m0 = blockIdx.y * 128, n0 = blockIdx.x * 128;
  const int ar = tid >> 3, aq = tid & 7;       // A staging: row base, float4 slot
  const int wm = wid >> 1, wn = wid & 1;       // wave grid 2x2
  const int fr = lane & 15, kg = lane >> 4;    // frag row/col, k-group

  f32x4 acc[4][4];
#pragma unroll
  for (int m = 0; m < 4; ++m)
#pragma unroll
    for (int n = 0; n < 4; ++n) acc[m][n] = (f32x4){0.f, 0.f, 0.f, 0.f};

  for (int k0 = 0; k0 < DDIM; k0 += 32) {
    // ---- stage: A fp32 loads first, then B gload_lds (latency overlap) ----
    float4 av[4];
#pragma unroll
    for (int i = 0; i < 4; ++i)
      av[i] = *(const float4*)&X[(size_t)(m0 + ar + i * 32) * DDIM + k0 + aq * 4];
#pragma unroll
    for (int j = 0; j < 4; ++j) {
      const int c = wid * 4 + j;                 // 16 chunks: 8 Bh + 8 Bl
      const int r0 = (c & 7) * 16;
      const int row = r0 + (lane >> 2);
      const int s = lane & 3;
      const size_t goff = (size_t)(n0 + row) * DDIM + k0 + ((s ^ (row & 3)) << 3);
      if (c < 8) GLOAD16(Wh + goff, &sBh[r0][0]);
      else       GLOAD16(Wl + goff, &sBl[r0][0]);
    }
#pragma unroll
    for (int i = 0; i < 4; ++i) {
      const int row = ar + i * 32;
      const int sl = (((aq >> 1) ^ (row & 3)) << 3) + ((aq & 1) << 2);
      ushort4 hv, lv;
      hv.x = f2bfu(av[i].x); lv.x = f2bfu(av[i].x - bfu2f(hv.x));
      hv.y = f2bfu(av[i].y); lv.y = f2bfu(av[i].y - bfu2f(hv.y));
      hv.z = f2bfu(av[i].z); lv.z = f2bfu(av[i].z - bfu2f(hv.z));
      hv.w = f2bfu(av[i].w); lv.w = f2bfu(av[i].w - bfu2f(hv.w));
      *(ushort4*)&sAh[row][sl] = hv;
      *(ushort4*)&sAl[row][sl] = lv;
    }
    __syncthreads();   // drains vmcnt (gload_lds) + lgkm (ds_write)

    // ---- compute: 16 ds_read_b128 + 48 MFMA per wave ----
    short8v ah[4], al[4], bh[4], bl[4];
#pragma unroll
    for (int m = 0; m < 4; ++m) {
      const int row = wm * 64 + m * 16 + fr;
      const int so = (kg ^ (row & 3)) << 3;
      ah[m] = *(const short8v*)&sAh[row][so];
      al[m] = *(const short8v*)&sAl[row][so];
    }
#pragma unroll
    for (int n = 0; n < 4; ++n) {
      const int col = wn * 64 + n * 16 + fr;
      const int so = (kg ^ (col & 3)) << 3;
      bh[n] = *(const short8v*)&sBh[col][so];
      bl[n] = *(const short8v*)&sBl[col][so];
    }
#pragma unroll
    for (int m = 0; m < 4; ++m)
#pragma unroll
      for (int n = 0; n < 4; ++n) {
        acc[m][n] = __builtin_amdgcn_mfma_f32_16x16x32_bf16(ah[m], bh[n], acc[m][n], 0, 0, 0);
        acc[m][n] = __builtin_amdgcn_mfma_f32_16x16x32_bf16(ah[m], bl[n], acc[m][n], 0, 0, 0);
        acc[m][n] = __builtin_amdgcn_mfma_f32_16x16x32_bf16(al[m], bh[n], acc[m][n], 0, 0, 0);
      }
    __syncthreads();   // all reads done before next stage overwrites
  }

  // ---- epilogue: C/D layout col=lane&15, row=(lane>>4)*4+reg (m89) ----
  const int isV = (n0 >= 2048);
#pragma unroll
  for (int m = 0; m < 4; ++m)
#pragma unroll
    for (int n = 0; n < 4; ++n) {
      const int col = n0 + wn * 64 + n * 16 + fr;
      const float bz = bias[col];
#pragma unroll
      for (int r = 0; r < 4; ++r) {
        const int row = m0 + wm * 64 + m * 16 + kg * 4 + r;
        const float v = acc[m][n][r] + bz;
        if (!isV) {
          QK[(size_t)row * 2048 + col] = v;
        } else {
          const size_t o = (size_t)row * 1024 + (col - 2048);
          const ushort h = f2bfu(v);
          Vh[o] = h;
          Vl[o] = f2bfu(v - bfu2f(h));
        }
      }
    }
}

// ---------------------------------------------------------------------------
// GEMM2 (batched over b): out[t,b,:] = v[t,b,:] @ Weff_b^T + bout.
// All operands pre-split bf16 hi/lo, staged via gload_lds.
// A rows: Vh/Vl[(t*4+b)*1024]; B: Weh/Wel[b][1024][1024]; C: out[(t*4+b)*1024].
// ---------------------------------------------------------------------------
__global__ __launch_bounds__(256, 2)
void gemm2_mfma(const ushort* __restrict__ Vh, const ushort* __restrict__ Vl,
                const ushort* __restrict__ Weh, const ushort* __restrict__ Wel,
                const float* __restrict__ bias, float* __restrict__ Out)
{
  __shared__ ushort sAh[128][32], sAl[128][32], sBh[128][32], sBl[128][32];
  const int tid = threadIdx.x;
  const int lane = tid & 63, wid = tid >> 6;
  const int m0 = blockIdx.y * 128, n0 = blockIdx.x * 128, bb = blockIdx.z;
  const int wm = wid >> 1, wn = wid & 1;
  const int fr = lane & 15, kg = lane >> 4;

  f32x4 acc[4][4];
#pragma unroll
  for (int m = 0; m < 4; ++m)
#pragma unroll
    for (int n = 0; n < 4; ++n) acc[m][n] = (f32x4){0.f, 0.f, 0.f, 0.f};

  const size_t wB = (size_t)bb * DDIM * DDIM;

  for (int k0 = 0; k0 < DDIM; k0 += 32) {
#pragma unroll
    for (int j = 0; j < 8; ++j) {          // wave w stages tile w, 8 chunks
      const int r0 = j * 16;
      const int row = r0 + (lane >> 2);
      const int s = lane & 3;
      const int ks = k0 + ((s ^ (row & 3)) << 3);
      if (wid == 0)
        GLOAD16(Vh + (size_t)((m0 + row) * 4 + bb) * 1024 + ks, &sAh[r0][0]);
      else if (wid == 1)
        GLOAD16(Vl + (size_t)((m0 + row) * 4 + bb) * 1024 + ks, &sAl[r0][0]);
      else if (wid == 2)
        GLOAD16(Weh + wB + (size_t)(n0 + row) * 1024 + ks, &sBh[r0][0]);
      else
        GLOAD16(Wel + wB + (size_t)(n0 + row) * 1024 + ks, &sBl[r0][0]);
    }
    __syncthreads();

    short8v ah[4], al[4], bh[4], bl[4];
#pragma unroll
    for (int m = 0; m < 4; ++m) {
      const int row = wm * 64 + m * 16 + fr;
      const int so = (kg ^ (row & 3)) << 3;
      ah[m] = *(const short8v*)&sAh[row][so];
      al[m] = *(const short8v*)&sAl[row][so];
    }
#pragma unroll
    for (int n = 0; n < 4; ++n) {
      const int col = wn * 64 + n * 16 + fr;
      const int so = (kg ^ (col & 3)) << 3;
      bh[n] = *(const short8v*)&sBh[col][so];
      bl[n] = *(const short8v*)&sBl[col][so];
    }
#pragma unroll
    for (int m = 0; m < 4; ++m)
#pragma unroll
      for (int n = 0; n < 4; ++n) {
        acc[m][n] = __builtin_amdgcn_mfma_f32_16x16x32_bf16(ah[m], bh[n], acc[m][n], 0, 0, 0);
        acc[m][n] = __builtin_amdgcn_mfma_f32_16x16x32_bf16(ah[m], bl[n], acc[m][n], 0, 0, 0);
        acc[m][n] = __builtin_amdgcn_mfma_f32_16x16x32_bf16(al[m], bh[n], acc[m][n], 0, 0, 0);
      }
    __syncthreads();
  }

  float* Ob = Out + (size_t)bb * 1024;     // row t -> offset t*4096
#pragma unroll
  for (int m = 0; m < 4; ++m)
#pragma unroll
    for (int n = 0; n < 4; ++n) {
      const int col = n0 + wn * 64 + n * 16 + fr;
      const float bz = bias[col];
#pragma unroll
      for (int r = 0; r < 4; ++r) {
        const int row = m0 + wm * 64 + m * 16 + kg * 4 + r;
        Ob[(size_t)row * 4096 + col] = acc[m][n][r] + bz;
      }
    }
}

// ---------------------------------------------------------------------------
// Correlation partials: grid (64 bh, 16 seg), 1 wave per block. Reads fp32 QK
// (row stride 8192: q at b*2048+h*64, k at +1024). Record: 4352 floats.
// ---------------------------------------------------------------------------
__global__ __launch_bounds__(64)
void corr_partial(const float* __restrict__ QK, float* __restrict__ P)
{
  __shared__ float qs[32][64];
  __shared__ float ks[32][64];
  const int bh  = blockIdx.x;
  const int seg = blockIdx.y;
  const int b = bh >> 4;
  const int h = bh & 15;
  const int lane = threadIdx.x;
  const float* qb = QK + (size_t)b * 2048 + h * HD;   // + t*8192
  const float* kb = qb + 1024;
  const int ty = lane >> 3;
  const int tx = lane & 7;
  const int rr = lane >> 4;
  const int cq = lane & 15;

  float acc[8][8];
#pragma unroll
  for (int i = 0; i < 8; ++i)
#pragma unroll
    for (int j = 0; j < 8; ++j) acc[i][j] = 0.f;
  float sQ[4]  = {0,0,0,0}, sK[4]  = {0,0,0,0};
  float sQ2[4] = {0,0,0,0}, sK2[4] = {0,0,0,0};

  for (int c = 0; c < 8; ++c) {
    const int tbase = seg * 256 + c * 32;
    float4 qv[8], kv[8];
#pragma unroll
    for (int i = 0; i < 8; ++i) {
      const size_t g = (size_t)(tbase + rr + i*4) * 8192 + cq * 4;
      qv[i] = *(const float4*)&qb[g];
      kv[i] = *(const float4*)&kb[g];
    }
    __syncthreads();
#pragma unroll
    for (int i = 0; i < 8; ++i) {
      const int row = rr + i*4;
      *(float4*)&qs[row][cq*4] = qv[i];
      *(float4*)&ks[row][cq*4] = kv[i];
      sQ[0] += qv[i].x; sQ[1] += qv[i].y; sQ[2] += qv[i].z; sQ[3] += qv[i].w;
      sK[0] += kv[i].x; sK[1] += kv[i].y; sK[2] += kv[i].z; sK[3] += kv[i].w;
      sQ2[0] = fmaf(qv[i].x, qv[i].x, sQ2[0]); sQ2[1] = fmaf(qv[i].y, qv[i].y, sQ2[1]);
      sQ2[2] = fmaf(qv[i].z, qv[i].z, sQ2[2]); sQ2[3] = fmaf(qv[i].w, qv[i].w, sQ2[3]);
      sK2[0] = fmaf(kv[i].x, kv[i].x, sK2[0]); sK2[1] = fmaf(kv[i].y, kv[i].y, sK2[1]);
      sK2[2] = fmaf(kv[i].z, kv[i].z, sK2[2]); sK2[3] = fmaf(kv[i].w, kv[i].w, sK2[3]);
    }
    __syncthreads();
#pragma unroll 8
    for (int t = 0; t < 32; ++t) {
      const float4 qa  = *(const float4*)&qs[t][ty*8];
      const float4 qb4 = *(const float4*)&qs[t][ty*8+4];
      const float4 ka  = *(const float4*)&ks[t][tx*8];
      const float4 kb4 = *(const float4*)&ks[t][tx*8+4];
      const float av[8] = {qa.x, qa.y, qa.z, qa.w, qb4.x, qb4.y, qb4.z, qb4.w};
      const float bv[8] = {ka.x, ka.y, ka.z, ka.w, kb4.x, kb4.y, kb4.z, kb4.w};
#pragma unroll
      for (int i = 0; i < 8; ++i)
#pragma unroll
        for (int j = 0; j < 8; ++j)
          acc[i][j] = fmaf(av[i], bv[j], acc[i][j]);
    }
  }

#pragma unroll
  for (int j = 0; j < 4; ++j) {
    sQ[j]  += __shfl_xor(sQ[j], 16, 64);  sQ[j]  += __shfl_xor(sQ[j], 32, 64);
    sK[j]  += __shfl_xor(sK[j], 16, 64);  sK[j]  += __shfl_xor(sK[j], 32, 64);
    sQ2[j] += __shfl_xor(sQ2[j], 16, 64); sQ2[j] += __shfl_xor(sQ2[j], 32, 64);
    sK2[j] += __shfl_xor(sK2[j], 16, 64); sK2[j] += __shfl_xor(sK2[j], 32, 64);
  }

  float* Pb = P + (size_t)(bh * 16 + seg) * 4352;
#pragma unroll
  for (int i = 0; i < 8; ++i) {
    const int row = ty*8 + i;
    float4 o0, o1;
    o0.x = acc[i][0]; o0.y = acc[i][1]; o0.z = acc[i][2]; o0.w = acc[i][3];
    o1.x = acc[i][4]; o1.y = acc[i][5]; o1.z = acc[i][6]; o1.w = acc[i][7];
    *(float4*)&Pb[row*64 + tx*8]     = o0;
    *(float4*)&Pb[row*64 + tx*8 + 4] = o1;
  }
  if (lane < 16) {
    float4 q4; q4.x = sQ[0];  q4.y = sQ[1];  q4.z = sQ[2];  q4.w = sQ[3];
    float4 k4; k4.x = sK[0];  k4.y = sK[1];  k4.z = sK[2];  k4.w = sK[3];
    float4 q2; q2.x = sQ2[0]; q2.y = sQ2[1]; q2.z = sQ2[2]; q2.w = sQ2[3];
    float4 k2; k2.x = sK2[0]; k2.y = sK2[1]; k2.z = sK2[2]; k2.w = sK2[3];
    *(float4*)&Pb[4096 + lane*4] = q4;
    *(float4*)&Pb[4160 + lane*4] = k4;
    *(float4*)&Pb[4224 + lane*4] = q2;
    *(float4*)&Pb[4288 + lane*4] = k2;
  }
}

// ---------------------------------------------------------------------------
// Finalize: sum 16 segment partials; corr = clip((c-SqSk/T)/sqrt(sx*sy),-1,1)
// ---------------------------------------------------------------------------
__global__ __launch_bounds__(256)
void corr_finalize(const float* __restrict__ P, float* __restrict__ corr)
{
  __shared__ float fin[4][64];
  const int bh = blockIdx.x;
  const int tid = threadIdx.x;
  const float* Pb = P + (size_t)bh * 16 * 4352;

  float s = 0.f;
  for (int seg = 0; seg < 16; ++seg) s += Pb[(size_t)seg*4352 + 4096 + tid];
  fin[tid >> 6][tid & 63] = s;

  float cacc[16];
#pragma unroll
  for (int i = 0; i < 16; ++i) cacc[i] = 0.f;
  for (int seg = 0; seg < 16; ++seg) {
#pragma unroll
    for (int i = 0; i < 16; ++i)
      cacc[i] += Pb[(size_t)seg*4352 + tid + i*256];
  }
  __syncthreads();

  const float invT = 1.0f / (float)TDIM;
#pragma unroll
  for (int i = 0; i < 16; ++i) {
    const int f = tid + i*256;
    const int d = f >> 6, e = f & 63;
    const float sq = fin[0][d], sk = fin[1][e];
    const float sq2 = fin[2][d], sk2 = fin[3][e];
    const float cc = cacc[i] - sq * sk * invT;
    const float sx = sq2 - sq * sq * invT;
    const float sy = sk2 - sk * sk * invT;
    float v = cc / sqrtf(sx * sy);
    v = fminf(1.f, fmaxf(-1.f, v));
    corr[(size_t)bh * 4096 + f] = v;
  }
}

// ---------------------------------------------------------------------------
// Weff_b[n][h*64+d] = sum_e corr[b,h][d][e] * Wout[n][h*64+e]  (fp32)
// ---------------------------------------------------------------------------
__global__ __launch_bounds__(256)
void weff_kernel(const float* __restrict__ corr, const float* __restrict__ Wout,
                 float* __restrict__ Weff)
{
  __shared__ float cs[64][64];
  __shared__ float ws[128][64];
  const int bh = blockIdx.x;
  const int b = bh >> 4, h = bh & 15;
  const int n0 = blockIdx.y * 128;
  const int tid = threadIdx.x;

  const float* cb = corr + (size_t)bh * 4096;
  float4* csv = (float4*)&cs[0][0];
#pragma unroll
  for (int i = 0; i < 4; ++i)
    csv[tid + 256*i] = ((const float4*)cb)[tid + 256*i];

  const int wr = tid >> 1, wh = (tid & 1) * 32;
  const float* wrow = Wout + (size_t)(n0 + wr) * DDIM + h * HD + wh;
#pragma unroll
  for (int i = 0; i < 8; ++i)
    *(float4*)&ws[wr][wh + i*4] = *(const float4*)&wrow[i*4];
  __syncthreads();

  const int ni = (tid >> 3) * 4;
  const int di = (tid & 7) * 8;
  float acc[4][8];
#pragma unroll
  for (int i = 0; i < 4; ++i)
#pragma unroll
    for (int j = 0; j < 8; ++j) acc[i][j] = 0.f;

  for (int e = 0; e < 64; ++e) {
    float wv[4], cv[8];
#pragma unroll
    for (int i = 0; i < 4; ++i) wv[i] = ws[ni + i][e];
#pragma unroll
    for (int j = 0; j < 8; ++j) cv[j] = cs[di + j][e];
#pragma unroll
    for (int i = 0; i < 4; ++i)
#pragma unroll
      for (int j = 0; j < 8; ++j)
        acc[i][j] = fmaf(wv[i], cv[j], acc[i][j]);
  }

  float* Wb = Weff + (size_t)b * DDIM * DDIM + h * HD;
#pragma unroll
  for (int i = 0; i < 4; ++i) {
    float4 o0, o1;
    o0.x = acc[i][0]; o0.y = acc[i][1]; o0.z = acc[i][2]; o0.w = acc[i][3];
    o1.x = acc[i][4]; o1.y = acc[i][5]; o1.z = acc[i][6]; o1.w = acc[i][7];
    *(float4*)&Wb[(size_t)(n0 + ni + i) * DDIM + di]     = o0;
    *(float4*)&Wb[(size_t)(n0 + ni + i) * DDIM + di + 4] = o1;
  }
}

// ---------------------------------------------------------------------------
extern "C" void kernel_launch(void* const* d_in, const int* in_sizes, int n_in,
                              void* d_out, int out_size, void* d_ws, size_t ws_size,
                              hipStream_t stream)
{
  (void)in_sizes; (void)n_in; (void)out_size; (void)ws_size;
  const float* x    = (const float*)d_in[0];
  const float* Wqkv = (const float*)d_in[1];
  const float* bqkv = (const float*)d_in[2];
  const float* Wout = (const float*)d_in[3];
  const float* bout = (const float*)d_in[4];
  float* out = (float*)d_out;

  // ws layout (bytes), total 236,978,176 B = 226.0 MiB (== proven round-1 size)
  //  [0,128M)   QK fp32 [16384][2048]
  //  [+32M+32M) Vh, Vl bf16 [16384][1024]
  //  [+1M)      corr fp32 [64][64][64]
  //  R1 17.0M   phase A: Wqh/Wql (12.6M) -> phase B: P (17.0M) -> phase C: Weff fp32 (16M)
  //  R2 16M     Weh/Wel bf16 [4][1024][1024]
  char* w = (char*)d_ws;
  float*  QK    = (float*)w;   w += (size_t)134217728;
  ushort* Vh    = (ushort*)w;  w += (size_t)33554432;
  ushort* Vl    = (ushort*)w;  w += (size_t)33554432;
  float*  corrB = (float*)w;   w += (size_t)1048576;
  char* R1 = w;                w += (size_t)17825792;
  char* R2 = w;
  ushort* Wqh   = (ushort*)R1;
  ushort* Wql   = Wqh + (size_t)3145728;
  float*  P     = (float*)R1;
  float*  WeffF = (float*)R1;
  ushort* Weh   = (ushort*)R2;
  ushort* Wel   = Weh + (size_t)4194304;

  // 1) split Wqkv -> bf16 hi/lo
  split_f32<<<dim3(1024), 256, 0, stream>>>(Wqkv, Wqh, Wql, 786432);
  // 2) qkv GEMM: q,k -> fp32 QK; v -> bf16 Vh/Vl
  gemm1_mfma<<<dim3(24, 128), 256, 0, stream>>>(x, Wqh, Wql, bqkv, QK, Vh, Vl);
  // 3) correlation partials (P overwrites Wq splits - dead after GEMM1)
  corr_partial<<<dim3(64, 16), 64, 0, stream>>>(QK, P);
  // 4) finalize corr
  corr_finalize<<<dim3(64), 256, 0, stream>>>(P, corrB);
  // 5) Weff_b = fold(corr_b, Wout) fp32 (overwrites P - dead after finalize)
  weff_kernel<<<dim3(64, 8), 256, 0, stream>>>(corrB, Wout, WeffF);
  // 6) split Weff -> bf16 hi/lo
  split_f32<<<dim3(1024), 256, 0, stream>>>(WeffF, Weh, Wel, 1048576);
  // 7) out = v @ Weff_b^T + bout (batched over b)
  gemm2_mfma<<<dim3(8, 32, 4), 256, 0, stream>>>(Vh, Vl, Weh, Wel, bout, out);
}

// Round 4
// 659.182 us; speedup vs baseline: 2.6006x; 1.0122x over previous
//
#include <hip/hip_runtime.h>
#include <hip/hip_bf16.h>

// Problem constants (fixed by setup_inputs)
#define TDIM 4096
#define BDIM 4
#define DDIM 1024
#define HDIM 16
#define HD   64
#define MDIM (TDIM * BDIM)      // 16384 rows (t,b)

typedef __attribute__((ext_vector_type(8))) short short8v;  // 8 bf16 bits = 4 VGPR
typedef __attribute__((ext_vector_type(4))) float f32x4;

__device__ __forceinline__ ushort f2bfu(float f) {
  union { __hip_bfloat16 h; ushort u; } c;
  c.h = __float2bfloat16(f);
  return c.u;
}
__device__ __forceinline__ float bfu2f(ushort u) {
  union { ushort u; __hip_bfloat16 h; } c;
  c.u = u;
  return __bfloat162float(c.h);
}

// async global->LDS, 16B per lane; LDS dest = wave-uniform base + lane*16
#define GLOAD16(gp, lp) __builtin_amdgcn_global_load_lds( \
    (const __attribute__((address_space(1))) void*)(gp),  \
    (__attribute__((address_space(3))) void*)(lp), 16, 0, 0)

// LDS swizzle: g(row) = (row>>1)&3. Bank quad = 4*(row&1) + (slot^g(row))
// is bijective over 8 consecutive rows -> 2 lanes/quad on ds_read_b128 (free).
// (Old row&3 variant aliased rows 0,4,8,12 -> 4-way conflict.)
#define SWZ(row) (((row) >> 1) & 3)

// ---------------------------------------------------------------------------
// split fp32 -> bf16 hi/lo arrays (hi = bf16(x), lo = bf16(x - hi))
// ---------------------------------------------------------------------------
__global__ __launch_bounds__(256)
void split_f32(const float* __restrict__ in, ushort* __restrict__ hi,
               ushort* __restrict__ lo, int n4)
{
  int i = blockIdx.x * blockDim.x + threadIdx.x;
  const int stride = gridDim.x * blockDim.x;
  for (; i < n4; i += stride) {
    const float4 v = ((const float4*)in)[i];
    ushort4 h, l;
    h.x = f2bfu(v.x); l.x = f2bfu(v.x - bfu2f(h.x));
    h.y = f2bfu(v.y); l.y = f2bfu(v.y - bfu2f(h.y));
    h.z = f2bfu(v.z); l.z = f2bfu(v.z - bfu2f(h.z));
    h.w = f2bfu(v.w); l.w = f2bfu(v.w - bfu2f(h.w));
    ((ushort4*)hi)[i] = h;
    ((ushort4*)lo)[i] = l;
  }
}

// ---------------------------------------------------------------------------
// GEMM1: qkv = x @ Wqkv^T + bqkv via split-bf16 3-MFMA.
// A = x fp32 (reg-staged, split on the fly), B = pre-split Wh/Wl (gload_lds).
// Output: n<2048 -> fp32 QK[16384][2048]; n>=2048 -> bf16 hi/lo V[16384][1024].
// 128x128 tile, BK=32, 4 waves (2x2), each wave 4x4 frags of 16x16x32.
// ---------------------------------------------------------------------------
__global__ __launch_bounds__(256, 2)
void gemm1_mfma(const float* __restrict__ X, const ushort* __restrict__ Wh,
                const ushort* __restrict__ Wl, const float* __restrict__ bias,
                float* __restrict__ QK, ushort* __restrict__ Vh,
                ushort* __restrict__ Vl)
{
  __shared__ ushort sAh[128][32], sAl[128][32], sBh[128][32], sBl[128][32];
  const int tid = threadIdx.x;
  const int lane = tid & 63, wid = tid >> 6;
  const int m0 = blockIdx.y * 128, n0 = blockIdx.x * 128;
  const int ar = tid >> 3, aq = tid & 7;       // A staging: row base, float4 slot
  const int wm = wid >> 1, wn = wid & 1;       // wave grid 2x2
  const int fr = lane & 15, kg = lane >> 4;    // frag row/col, k-group

  f32x4 acc[4][4];
#pragma unroll
  for (int m = 0; m < 4; ++m)
#pragma unroll
    for (int n = 0; n < 4; ++n) acc[m][n] = (f32x4){0.f, 0.f, 0.f, 0.f};

  for (int k0 = 0; k0 < DDIM; k0 += 32) {
    // ---- stage: A fp32 loads first, then B gload_lds (latency overlap) ----
    float4 av[4];
#pragma unroll
    for (int i = 0; i < 4; ++i)
      av[i] = *(const float4*)&X[(size_t)(m0 + ar + i * 32) * DDIM + k0 + aq * 4];
#pragma unroll
    for (int j = 0; j < 4; ++j) {
      const int c = wid * 4 + j;                 // 16 chunks: 8 Bh + 8 Bl
      const int r0 = (c & 7) * 16;
      const int row = r0 + (lane >> 2);
      const int s = lane & 3;
      const size_t goff = (size_t)(n0 + row) * DDIM + k0 + ((s ^ SWZ(row)) << 3);
      if (c < 8) GLOAD16(Wh + goff, &sBh[r0][0]);
      else       GLOAD16(Wl + goff, &sBl[r0][0]);
    }
#pragma unroll
    for (int i = 0; i < 4; ++i) {
      const int row = ar + i * 32;
      const int sl = (((aq >> 1) ^ SWZ(row)) << 3) + ((aq & 1) << 2);
      ushort4 hv, lv;
      hv.x = f2bfu(av[i].x); lv.x = f2bfu(av[i].x - bfu2f(hv.x));
      hv.y = f2bfu(av[i].y); lv.y = f2bfu(av[i].y - bfu2f(hv.y));
      hv.z = f2bfu(av[i].z); lv.z = f2bfu(av[i].z - bfu2f(hv.z));
      hv.w = f2bfu(av[i].w); lv.w = f2bfu(av[i].w - bfu2f(hv.w));
      *(ushort4*)&sAh[row][sl] = hv;
      *(ushort4*)&sAl[row][sl] = lv;
    }
    __syncthreads();   // drains vmcnt (gload_lds) + lgkm (ds_write)

    // ---- compute: 16 ds_read_b128 + 48 MFMA per wave ----
    short8v ah[4], al[4], bh[4], bl[4];
#pragma unroll
    for (int m = 0; m < 4; ++m) {
      const int row = wm * 64 + m * 16 + fr;
      const int so = (kg ^ SWZ(row)) << 3;
      ah[m] = *(const short8v*)&sAh[row][so];
      al[m] = *(const short8v*)&sAl[row][so];
    }
#pragma unroll
    for (int n = 0; n < 4; ++n) {
      const int col = wn * 64 + n * 16 + fr;
      const int so = (kg ^ SWZ(col)) << 3;
      bh[n] = *(const short8v*)&sBh[col][so];
      bl[n] = *(const short8v*)&sBl[col][so];
    }
#pragma unroll
    for (int m = 0; m < 4; ++m)
#pragma unroll
      for (int n = 0; n < 4; ++n) {
        acc[m][n] = __builtin_amdgcn_mfma_f32_16x16x32_bf16(ah[m], bh[n], acc[m][n], 0, 0, 0);
        acc[m][n] = __builtin_amdgcn_mfma_f32_16x16x32_bf16(ah[m], bl[n], acc[m][n], 0, 0, 0);
        acc[m][n] = __builtin_amdgcn_mfma_f32_16x16x32_bf16(al[m], bh[n], acc[m][n], 0, 0, 0);
      }
    __syncthreads();   // all reads done before next stage overwrites
  }

  // ---- epilogue: C/D layout col=lane&15, row=(lane>>4)*4+reg (m89) ----
  const int isV = (n0 >= 2048);
#pragma unroll
  for (int m = 0; m < 4; ++m)
#pragma unroll
    for (int n = 0; n < 4; ++n) {
      const int col = n0 + wn * 64 + n * 16 + fr;
      const float bz = bias[col];
#pragma unroll
      for (int r = 0; r < 4; ++r) {
        const int row = m0 + wm * 64 + m * 16 + kg * 4 + r;
        const float v = acc[m][n][r] + bz;
        if (!isV) {
          QK[(size_t)row * 2048 + col] = v;
        } else {
          const size_t o = (size_t)row * 1024 + (col - 2048);
          const ushort h = f2bfu(v);
          Vh[o] = h;
          Vl[o] = f2bfu(v - bfu2f(h));
        }
      }
    }
}

// ---------------------------------------------------------------------------
// GEMM2 (batched over b): out[t,b,:] = v[t,b,:] @ Weff_b^T + bout.
// All operands pre-split bf16 hi/lo, staged via gload_lds.
// ---------------------------------------------------------------------------
__global__ __launch_bounds__(256, 2)
void gemm2_mfma(const ushort* __restrict__ Vh, const ushort* __restrict__ Vl,
                const ushort* __restrict__ Weh, const ushort* __restrict__ Wel,
                const float* __restrict__ bias, float* __restrict__ Out)
{
  __shared__ ushort sAh[128][32], sAl[128][32], sBh[128][32], sBl[128][32];
  const int tid = threadIdx.x;
  const int lane = tid & 63, wid = tid >> 6;
  const int m0 = blockIdx.y * 128, n0 = blockIdx.x * 128, bb = blockIdx.z;
  const int wm = wid >> 1, wn = wid & 1;
  const int fr = lane & 15, kg = lane >> 4;

  f32x4 acc[4][4];
#pragma unroll
  for (int m = 0; m < 4; ++m)
#pragma unroll
    for (int n = 0; n < 4; ++n) acc[m][n] = (f32x4){0.f, 0.f, 0.f, 0.f};

  const size_t wB = (size_t)bb * DDIM * DDIM;

  for (int k0 = 0; k0 < DDIM; k0 += 32) {
#pragma unroll
    for (int j = 0; j < 8; ++j) {          // wave w stages tile w, 8 chunks
      const int r0 = j * 16;
      const int row = r0 + (lane >> 2);
      const int s = lane & 3;
      const int ks = k0 + ((s ^ SWZ(row)) << 3);
      if (wid == 0)
        GLOAD16(Vh + (size_t)((m0 + row) * 4 + bb) * 1024 + ks, &sAh[r0][0]);
      else if (wid == 1)
        GLOAD16(Vl + (size_t)((m0 + row) * 4 + bb) * 1024 + ks, &sAl[r0][0]);
      else if (wid == 2)
        GLOAD16(Weh + wB + (size_t)(n0 + row) * 1024 + ks, &sBh[r0][0]);
      else
        GLOAD16(Wel + wB + (size_t)(n0 + row) * 1024 + ks, &sBl[r0][0]);
    }
    __syncthreads();

    short8v ah[4], al[4], bh[4], bl[4];
#pragma unroll
    for (int m = 0; m < 4; ++m) {
      const int row = wm * 64 + m * 16 + fr;
      const int so = (kg ^ SWZ(row)) << 3;
      ah[m] = *(const short8v*)&sAh[row][so];
      al[m] = *(const short8v*)&sAl[row][so];
    }
#pragma unroll
    for (int n = 0; n < 4; ++n) {
      const int col = wn * 64 + n * 16 + fr;
      const int so = (kg ^ SWZ(col)) << 3;
      bh[n] = *(const short8v*)&sBh[col][so];
      bl[n] = *(const short8v*)&sBl[col][so];
    }
#pragma unroll
    for (int m = 0; m < 4; ++m)
#pragma unroll
      for (int n = 0; n < 4; ++n) {
        acc[m][n] = __builtin_amdgcn_mfma_f32_16x16x32_bf16(ah[m], bh[n], acc[m][n], 0, 0, 0);
        acc[m][n] = __builtin_amdgcn_mfma_f32_16x16x32_bf16(ah[m], bl[n], acc[m][n], 0, 0, 0);
        acc[m][n] = __builtin_amdgcn_mfma_f32_16x16x32_bf16(al[m], bh[n], acc[m][n], 0, 0, 0);
      }
    __syncthreads();
  }

  float* Ob = Out + (size_t)bb * 1024;     // row t -> offset t*4096
#pragma unroll
  for (int m = 0; m < 4; ++m)
#pragma unroll
    for (int n = 0; n < 4; ++n) {
      const int col = n0 + wn * 64 + n * 16 + fr;
      const float bz = bias[col];
#pragma unroll
      for (int r = 0; r < 4; ++r) {
        const int row = m0 + wm * 64 + m * 16 + kg * 4 + r;
        Ob[(size_t)row * 4096 + col] = acc[m][n][r] + bz;
      }
    }
}

// ---------------------------------------------------------------------------
// Correlation partials: grid (64 bh, 16 seg), 256 threads = 4 waves.
// Each wave owns a private 16-t staging slice -> NO barriers in the t-loop
// (within-wave LDS ordering is hardware-guaranteed); 16 waves/CU occupancy
// (vs 4 before: was latency-bound on strided HBM reads).
// Cross-wave c-reduction via LDS overlay, then one record per block.
// Record: 4096 c + 256 sums = 4352 floats (layout unchanged).
// ---------------------------------------------------------------------------
__global__ __launch_bounds__(256)
void corr_partial(const float* __restrict__ QK, float* __restrict__ P)
{
  __shared__ float qs[4][16][64];    // 16 KB; reused as cbuf[64][64] after loop
  __shared__ float ks[4][16][64];    // 16 KB
  __shared__ float ssum[4][4][64];   // 4 KB: per-wave {Sq,Sk,Sq2,Sk2}
  const int bh  = blockIdx.x;
  const int seg = blockIdx.y;
  const int b = bh >> 4;
  const int h = bh & 15;
  const int tid = threadIdx.x;
  const int wid = tid >> 6, lane = tid & 63;
  const float* qb = QK + (size_t)b * 2048 + h * HD;   // + t*8192
  const float* kb = qb + 1024;
  const int ty = lane >> 3;    // 0..7 -> d rows ty*8..+8
  const int tx = lane & 7;     // 0..7 -> e cols tx*8..+8
  const int rr = lane >> 4;    // staging row base 0..3
  const int cq = lane & 15;    // staging float4 col

  float acc[8][8];
#pragma unroll
  for (int i = 0; i < 8; ++i)
#pragma unroll
    for (int j = 0; j < 8; ++j) acc[i][j] = 0.f;
  float sQ[4]  = {0,0,0,0}, sK[4]  = {0,0,0,0};
  float sQ2[4] = {0,0,0,0}, sK2[4] = {0,0,0,0};

  for (int c = 0; c < 4; ++c) {      // wave handles 4 chunks of 16 t
    const int tbase = seg * 256 + wid * 64 + c * 16;
    float4 qv[4], kv[4];
#pragma unroll
    for (int i = 0; i < 4; ++i) {
      const size_t g = (size_t)(tbase + rr + i*4) * 8192 + cq * 4;
      qv[i] = *(const float4*)&qb[g];
      kv[i] = *(const float4*)&kb[g];
    }
#pragma unroll
    for (int i = 0; i < 4; ++i) {
      const int row = rr + i*4;
      *(float4*)&qs[wid][row][cq*4] = qv[i];
      *(float4*)&ks[wid][row][cq*4] = kv[i];
      sQ[0] += qv[i].x; sQ[1] += qv[i].y; sQ[2] += qv[i].z; sQ[3] += qv[i].w;
      sK[0] += kv[i].x; sK[1] += kv[i].y; sK[2] += kv[i].z; sK[3] += kv[i].w;
      sQ2[0] = fmaf(qv[i].x, qv[i].x, sQ2[0]); sQ2[1] = fmaf(qv[i].y, qv[i].y, sQ2[1]);
      sQ2[2] = fmaf(qv[i].z, qv[i].z, sQ2[2]); sQ2[3] = fmaf(qv[i].w, qv[i].w, sQ2[3]);
      sK2[0] = fmaf(kv[i].x, kv[i].x, sK2[0]); sK2[1] = fmaf(kv[i].y, kv[i].y, sK2[1]);
      sK2[2] = fmaf(kv[i].z, kv[i].z, sK2[2]); sK2[3] = fmaf(kv[i].w, kv[i].w, sK2[3]);
    }
#pragma unroll 8
    for (int t = 0; t < 16; ++t) {
      const float4 qa  = *(const float4*)&qs[wid][t][ty*8];
      const float4 qb4 = *(const float4*)&qs[wid][t][ty*8+4];
      const float4 ka  = *(const float4*)&ks[wid][t][tx*8];
      const float4 kb4 = *(const float4*)&ks[wid][t][tx*8+4];
      const float av[8] = {qa.x, qa.y, qa.z, qa.w, qb4.x, qb4.y, qb4.z, qb4.w};
      const float bv[8] = {ka.x, ka.y, ka.z, ka.w, kb4.x, kb4.y, kb4.z, kb4.w};
#pragma unroll
      for (int i = 0; i < 8; ++i)
#pragma unroll
        for (int j = 0; j < 8; ++j)
          acc[i][j] = fmaf(av[i], bv[j], acc[i][j]);
    }
  }

  // per-wave sum reduce across lanes {cq, cq+16, cq+32, cq+48}
#pragma unroll
  for (int j = 0; j < 4; ++j) {
    sQ[j]  += __shfl_xor(sQ[j], 16, 64);  sQ[j]  += __shfl_xor(sQ[j], 32, 64);
    sK[j]  += __shfl_xor(sK[j], 16, 64);  sK[j]  += __shfl_xor(sK[j], 32, 64);
    sQ2[j] += __shfl_xor(sQ2[j], 16, 64); sQ2[j] += __shfl_xor(sQ2[j], 32, 64);
    sK2[j] += __shfl_xor(sK2[j], 16, 64); sK2[j] += __shfl_xor(sK2[j], 32, 64);
  }
  if (lane < 16) {
    float4 q4; q4.x = sQ[0];  q4.y = sQ[1];  q4.z = sQ[2];  q4.w = sQ[3];
    float4 k4; k4.x = sK[0];  k4.y = sK[1];  k4.z = sK[2];  k4.w = sK[3];
    float4 q2; q2.x = sQ2[0]; q2.y = sQ2[1]; q2.z = sQ2[2]; q2.w = sQ2[3];
    float4 k2; k2.x = sK2[0]; k2.y = sK2[1]; k2.z = sK2[2]; k2.w = sK2[3];
    *(float4*)&ssum[wid][0][lane*4] = q4;
    *(float4*)&ssum[wid][1][lane*4] = k4;
    *(float4*)&ssum[wid][2][lane*4] = q2;
    *(float4*)&ssum[wid][3][lane*4] = k2;
  }

  // cross-wave c reduction into cbuf (overlays qs; all staging reads done)
  float* cbuf = &qs[0][0][0];
  __syncthreads();
#pragma unroll
  for (int w = 0; w < 4; ++w) {
    if (wid == w) {
#pragma unroll
      for (int i = 0; i < 8; ++i) {
        float* p0 = &cbuf[(ty*8 + i) * 64 + tx*8];
        if (w == 0) {
          float4 o0, o1;
          o0.x = acc[i][0]; o0.y = acc[i][1]; o0.z = acc[i][2]; o0.w = acc[i][3];
          o1.x = acc[i][4]; o1.y = acc[i][5]; o1.z = acc[i][6]; o1.w = acc[i][7];
          *(float4*)p0 = o0; *(float4*)(p0 + 4) = o1;
        } else {
          float4 o0 = *(const float4*)p0, o1 = *(const float4*)(p0 + 4);
          o0.x += acc[i][0]; o0.y += acc[i][1]; o0.z += acc[i][2]; o0.w += acc[i][3];
          o1.x += acc[i][4]; o1.y += acc[i][5]; o1.z += acc[i][6]; o1.w += acc[i][7];
          *(float4*)p0 = o0; *(float4*)(p0 + 4) = o1;
        }
      }
    }
    __syncthreads();
  }

  // write record: 4096 c + 256 sums
  float* Pb = P + (size_t)(bh * 16 + seg) * 4352;
#pragma unroll
  for (int i = 0; i < 4; ++i)
    ((float4*)Pb)[tid + 256*i] = ((const float4*)cbuf)[tid + 256*i];
  {
    const int comp = tid >> 6, d = tid & 63;
    Pb[4096 + tid] = ssum[0][comp][d] + ssum[1][comp][d] +
                     ssum[2][comp][d] + ssum[3][comp][d];
  }
}

// ---------------------------------------------------------------------------
// Finalize: sum 16 segment partials; corr = clip((c-SqSk/T)/sqrt(sx*sy),-1,1)
// ---------------------------------------------------------------------------
__global__ __launch_bounds__(256)
void corr_finalize(const float* __restrict__ P, float* __restrict__ corr)
{
  __shared__ float fin[4][64];
  const int bh = blockIdx.x;
  const int tid = threadIdx.x;
  const float* Pb = P + (size_t)bh * 16 * 4352;

  float s = 0.f;
  for (int seg = 0; seg < 16; ++seg) s += Pb[(size_t)seg*4352 + 4096 + tid];
  fin[tid >> 6][tid & 63] = s;

  float cacc[16];
#pragma unroll
  for (int i = 0; i < 16; ++i) cacc[i] = 0.f;
  for (int seg = 0; seg < 16; ++seg) {
#pragma unroll
    for (int i = 0; i < 16; ++i)
      cacc[i] += Pb[(size_t)seg*4352 + tid + i*256];
  }
  __syncthreads();

  const float invT = 1.0f / (float)TDIM;
#pragma unroll
  for (int i = 0; i < 16; ++i) {
    const int f = tid + i*256;
    const int d = f >> 6, e = f & 63;
    const float sq = fin[0][d], sk = fin[1][e];
    const float sq2 = fin[2][d], sk2 = fin[3][e];
    const float cc = cacc[i] - sq * sk * invT;
    const float sx = sq2 - sq * sq * invT;
    const float sy = sk2 - sk * sk * invT;
    float v = cc / sqrtf(sx * sy);
    v = fminf(1.f, fmaxf(-1.f, v));
    corr[(size_t)bh * 4096 + f] = v;
  }
}

// ---------------------------------------------------------------------------
// Weff_b[n][h*64+d] = sum_e corr[b,h][d][e] * Wout[n][h*64+e]  (fp32)
// ---------------------------------------------------------------------------
__global__ __launch_bounds__(256)
void weff_kernel(const float* __restrict__ corr, const float* __restrict__ Wout,
                 float* __restrict__ Weff)
{
  __shared__ float cs[64][64];
  __shared__ float ws[128][64];
  const int bh = blockIdx.x;
  const int b = bh >> 4, h = bh & 15;
  const int n0 = blockIdx.y * 128;
  const int tid = threadIdx.x;

  const float* cb = corr + (size_t)bh * 4096;
  float4* csv = (float4*)&cs[0][0];
#pragma unroll
  for (int i = 0; i < 4; ++i)
    csv[tid + 256*i] = ((const float4*)cb)[tid + 256*i];

  const int wr = tid >> 1, wh = (tid & 1) * 32;
  const float* wrow = Wout + (size_t)(n0 + wr) * DDIM + h * HD + wh;
#pragma unroll
  for (int i = 0; i < 8; ++i)
    *(float4*)&ws[wr][wh + i*4] = *(const float4*)&wrow[i*4];
  __syncthreads();

  const int ni = (tid >> 3) * 4;
  const int di = (tid & 7) * 8;
  float acc[4][8];
#pragma unroll
  for (int i = 0; i < 4; ++i)
#pragma unroll
    for (int j = 0; j < 8; ++j) acc[i][j] = 0.f;

  for (int e = 0; e < 64; ++e) {
    float wv[4], cv[8];
#pragma unroll
    for (int i = 0; i < 4; ++i) wv[i] = ws[ni + i][e];
#pragma unroll
    for (int j = 0; j < 8; ++j) cv[j] = cs[di + j][e];
#pragma unroll
    for (int i = 0; i < 4; ++i)
#pragma unroll
      for (int j = 0; j < 8; ++j)
        acc[i][j] = fmaf(wv[i], cv[j], acc[i][j]);
  }

  float* Wb = Weff + (size_t)b * DDIM * DDIM + h * HD;
#pragma unroll
  for (int i = 0; i < 4; ++i) {
    float4 o0, o1;
    o0.x = acc[i][0]; o0.y = acc[i][1]; o0.z = acc[i][2]; o0.w = acc[i][3];
    o1.x = acc[i][4]; o1.y = acc[i][5]; o1.z = acc[i][6]; o1.w = acc[i][7];
    *(float4*)&Wb[(size_t)(n0 + ni + i) * DDIM + di]     = o0;
    *(float4*)&Wb[(size_t)(n0 + ni + i) * DDIM + di + 4] = o1;
  }
}

// ---------------------------------------------------------------------------
extern "C" void kernel_launch(void* const* d_in, const int* in_sizes, int n_in,
                              void* d_out, int out_size, void* d_ws, size_t ws_size,
                              hipStream_t stream)
{
  (void)in_sizes; (void)n_in; (void)out_size; (void)ws_size;
  const float* x    = (const float*)d_in[0];
  const float* Wqkv = (const float*)d_in[1];
  const float* bqkv = (const float*)d_in[2];
  const float* Wout = (const float*)d_in[3];
  const float* bout = (const float*)d_in[4];
  float* out = (float*)d_out;

  // ws layout (bytes), total 236,978,176 B = 226.0 MiB (== proven size)
  //  [0,128M)   QK fp32 [16384][2048]
  //  [+32M+32M) Vh, Vl bf16 [16384][1024]
  //  [+1M)      corr fp32 [64][64][64]
  //  R1 17.0M   phase A: Wqh/Wql (12.6M) -> phase B: P (17.0M) -> phase C: Weff fp32 (16M)
  //  R2 16M     Weh/Wel bf16 [4][1024][1024]
  char* w = (char*)d_ws;
  float*  QK    = (float*)w;   w += (size_t)134217728;
  ushort* Vh    = (ushort*)w;  w += (size_t)33554432;
  ushort* Vl    = (ushort*)w;  w += (size_t)33554432;
  float*  corrB = (float*)w;   w += (size_t)1048576;
  char* R1 = w;                w += (size_t)17825792;
  char* R2 = w;
  ushort* Wqh   = (ushort*)R1;
  ushort* Wql   = Wqh + (size_t)3145728;
  float*  P     = (float*)R1;
  float*  WeffF = (float*)R1;
  ushort* Weh   = (ushort*)R2;
  ushort* Wel   = Weh + (size_t)4194304;

  // 1) split Wqkv -> bf16 hi/lo
  split_f32<<<dim3(1024), 256, 0, stream>>>(Wqkv, Wqh, Wql, 786432);
  // 2) qkv GEMM: q,k -> fp32 QK; v -> bf16 Vh/Vl
  gemm1_mfma<<<dim3(24, 128), 256, 0, stream>>>(x, Wqh, Wql, bqkv, QK, Vh, Vl);
  // 3) correlation partials (P overwrites Wq splits - dead after GEMM1)
  corr_partial<<<dim3(64, 16), 256, 0, stream>>>(QK, P);
  // 4) finalize corr
  corr_finalize<<<dim3(64), 256, 0, stream>>>(P, corrB);
  // 5) Weff_b = fold(corr_b, Wout) fp32 (overwrites P - dead after finalize)
  weff_kernel<<<dim3(64, 8), 256, 0, stream>>>(corrB, Wout, WeffF);
  // 6) split Weff -> bf16 hi/lo
  split_f32<<<dim3(1024), 256, 0, stream>>>(WeffF, Weh, Wel, 1048576);
  // 7) out = v @ Weff_b^T + bout (batched over b)
  gemm2_mfma<<<dim3(8, 32, 4), 256, 0, stream>>>(Vh, Vl, Weh, Wel, bout, out);
}

// Round 5
// 657.675 us; speedup vs baseline: 2.6066x; 1.0023x over previous
//
#include <hip/hip_runtime.h>
#include <hip/hip_bf16.h>

// Problem constants (fixed by setup_inputs)
#define TDIM 4096
#define BDIM 4
#define DDIM 1024
#define HDIM 16
#define HD   64
#define MDIM (TDIM * BDIM)      // 16384 rows (t,b)

typedef __attribute__((ext_vector_type(8))) short short8v;  // 8 bf16 bits = 4 VGPR
typedef __attribute__((ext_vector_type(4))) float f32x4;

__device__ __forceinline__ ushort f2bfu(float f) {
  union { __hip_bfloat16 h; ushort u; } c;
  c.h = __float2bfloat16(f);
  return c.u;
}
__device__ __forceinline__ float bfu2f(ushort u) {
  union { ushort u; __hip_bfloat16 h; } c;
  c.u = u;
  return __bfloat162float(c.h);
}

// async global->LDS, 16B per lane; LDS dest = wave-uniform base + lane*16
#define GLOAD16(gp, lp) __builtin_amdgcn_global_load_lds( \
    (const __attribute__((address_space(1))) void*)(gp),  \
    (__attribute__((address_space(3))) void*)(lp), 16, 0, 0)

// LDS swizzle: g(row) = (row>>1)&3. Bank quad = 4*(row&1) + (slot^g(row))
// is bijective over 8 consecutive rows -> 2 lanes/quad on ds_read_b128 (free).
// Verified r4: SQ_LDS_BANK_CONFLICT 2.5e7 -> 0.
#define SWZ(row) (((row) >> 1) & 3)

// ---------------------------------------------------------------------------
// split fp32 -> bf16 hi/lo arrays (hi = bf16(x), lo = bf16(x - hi))
// ---------------------------------------------------------------------------
__global__ __launch_bounds__(256)
void split_f32(const float* __restrict__ in, ushort* __restrict__ hi,
               ushort* __restrict__ lo, int n4)
{
  int i = blockIdx.x * blockDim.x + threadIdx.x;
  const int stride = gridDim.x * blockDim.x;
  for (; i < n4; i += stride) {
    const float4 v = ((const float4*)in)[i];
    ushort4 h, l;
    h.x = f2bfu(v.x); l.x = f2bfu(v.x - bfu2f(h.x));
    h.y = f2bfu(v.y); l.y = f2bfu(v.y - bfu2f(h.y));
    h.z = f2bfu(v.z); l.z = f2bfu(v.z - bfu2f(h.z));
    h.w = f2bfu(v.w); l.w = f2bfu(v.w - bfu2f(h.w));
    ((ushort4*)hi)[i] = h;
    ((ushort4*)lo)[i] = l;
  }
}

// ---------------------------------------------------------------------------
// GEMM1: qkv = x @ Wqkv^T + bqkv via split-bf16 3-MFMA.
// A = x fp32 (reg-staged, split on the fly), B = pre-split Wh/Wl (gload_lds).
// Output: q -> Qc[bh][t][64] fp32 (head-major, contiguous per (b,h));
//         k -> Kc[bh][t][64] fp32; v -> bf16 hi/lo V[16384][1024].
// Head-major q/k makes corr_partial's reads fully sequential (r4 post-mortem:
// the old row-interleaved layout left corr_partial at ~11% HBM efficiency).
// 128x128 tile, BK=32, 4 waves (2x2), each wave 4x4 frags of 16x16x32.
// ---------------------------------------------------------------------------
__global__ __launch_bounds__(256, 2)
void gemm1_mfma(const float* __restrict__ X, const ushort* __restrict__ Wh,
                const ushort* __restrict__ Wl, const float* __restrict__ bias,
                float* __restrict__ Qc, float* __restrict__ Kc,
                ushort* __restrict__ Vh, ushort* __restrict__ Vl)
{
  __shared__ ushort sAh[128][32], sAl[128][32], sBh[128][32], sBl[128][32];
  const int tid = threadIdx.x;
  const int lane = tid & 63, wid = tid >> 6;
  const int m0 = blockIdx.y * 128, n0 = blockIdx.x * 128;
  const int ar = tid >> 3, aq = tid & 7;       // A staging: row base, float4 slot
  const int wm = wid >> 1, wn = wid & 1;       // wave grid 2x2
  const int fr = lane & 15, kg = lane >> 4;    // frag row/col, k-group

  f32x4 acc[4][4];
#pragma unroll
  for (int m = 0; m < 4; ++m)
#pragma unroll
    for (int n = 0; n < 4; ++n) acc[m][n] = (f32x4){0.f, 0.f, 0.f, 0.f};

  for (int k0 = 0; k0 < DDIM; k0 += 32) {
    // ---- stage: A fp32 loads first, then B gload_lds (latency overlap) ----
    float4 av[4];
#pragma unroll
    for (int i = 0; i < 4; ++i)
      av[i] = *(const float4*)&X[(size_t)(m0 + ar + i * 32) * DDIM + k0 + aq * 4];
#pragma unroll
    for (int j = 0; j < 4; ++j) {
      const int c = wid * 4 + j;                 // 16 chunks: 8 Bh + 8 Bl
      const int r0 = (c & 7) * 16;
      const int row = r0 + (lane >> 2);
      const int s = lane & 3;
      const size_t goff = (size_t)(n0 + row) * DDIM + k0 + ((s ^ SWZ(row)) << 3);
      if (c < 8) GLOAD16(Wh + goff, &sBh[r0][0]);
      else       GLOAD16(Wl + goff, &sBl[r0][0]);
    }
#pragma unroll
    for (int i = 0; i < 4; ++i) {
      const int row = ar + i * 32;
      const int sl = (((aq >> 1) ^ SWZ(row)) << 3) + ((aq & 1) << 2);
      ushort4 hv, lv;
      hv.x = f2bfu(av[i].x); lv.x = f2bfu(av[i].x - bfu2f(hv.x));
      hv.y = f2bfu(av[i].y); lv.y = f2bfu(av[i].y - bfu2f(hv.y));
      hv.z = f2bfu(av[i].z); lv.z = f2bfu(av[i].z - bfu2f(hv.z));
      hv.w = f2bfu(av[i].w); lv.w = f2bfu(av[i].w - bfu2f(hv.w));
      *(ushort4*)&sAh[row][sl] = hv;
      *(ushort4*)&sAl[row][sl] = lv;
    }
    __syncthreads();   // drains vmcnt (gload_lds) + lgkm (ds_write)

    // ---- compute: 16 ds_read_b128 + 48 MFMA per wave ----
    short8v ah[4], al[4], bh[4], bl[4];
#pragma unroll
    for (int m = 0; m < 4; ++m) {
      const int row = wm * 64 + m * 16 + fr;
      const int so = (kg ^ SWZ(row)) << 3;
      ah[m] = *(const short8v*)&sAh[row][so];
      al[m] = *(const short8v*)&sAl[row][so];
    }
#pragma unroll
    for (int n = 0; n < 4; ++n) {
      const int col = wn * 64 + n * 16 + fr;
      const int so = (kg ^ SWZ(col)) << 3;
      bh[n] = *(const short8v*)&sBh[col][so];
      bl[n] = *(const short8v*)&sBl[col][so];
    }
#pragma unroll
    for (int m = 0; m < 4; ++m)
#pragma unroll
      for (int n = 0; n < 4; ++n) {
        acc[m][n] = __builtin_amdgcn_mfma_f32_16x16x32_bf16(ah[m], bh[n], acc[m][n], 0, 0, 0);
        acc[m][n] = __builtin_amdgcn_mfma_f32_16x16x32_bf16(ah[m], bl[n], acc[m][n], 0, 0, 0);
        acc[m][n] = __builtin_amdgcn_mfma_f32_16x16x32_bf16(al[m], bh[n], acc[m][n], 0, 0, 0);
      }
    __syncthreads();   // all reads done before next stage overwrites
  }

  // ---- epilogue: C/D layout col=lane&15, row=(lane>>4)*4+reg (m89) ----
  const int region = n0 >> 10;   // 0=q, 1=k, 2=v (128-tiles never straddle)
#pragma unroll
  for (int m = 0; m < 4; ++m)
#pragma unroll
    for (int n = 0; n < 4; ++n) {
      const int col = n0 + wn * 64 + n * 16 + fr;
      const float bz = bias[col];
      const int cc = col & 1023;
      const int hh = cc >> 6, dd = cc & 63;
#pragma unroll
      for (int r = 0; r < 4; ++r) {
        const int row = m0 + wm * 64 + m * 16 + kg * 4 + r;
        const float v = acc[m][n][r] + bz;
        const int t = row >> 2, b = row & 3;     // rows are (t,b) interleaved
        const size_t ho = (((size_t)(b * 16 + hh)) * 4096 + t) * 64 + dd;
        if (region == 0)      Qc[ho] = v;
        else if (region == 1) Kc[ho] = v;
        else {
          const size_t o = (size_t)row * 1024 + cc;
          const ushort h2 = f2bfu(v);
          Vh[o] = h2;
          Vl[o] = f2bfu(v - bfu2f(h2));
        }
      }
    }
}

// ---------------------------------------------------------------------------
// GEMM2 (batched over b): out[t,b,:] = v[t,b,:] @ Weff_b^T + bout.
// All operands pre-split bf16 hi/lo, staged via gload_lds.
// ---------------------------------------------------------------------------
__global__ __launch_bounds__(256, 2)
void gemm2_mfma(const ushort* __restrict__ Vh, const ushort* __restrict__ Vl,
                const ushort* __restrict__ Weh, const ushort* __restrict__ Wel,
                const float* __restrict__ bias, float* __restrict__ Out)
{
  __shared__ ushort sAh[128][32], sAl[128][32], sBh[128][32], sBl[128][32];
  const int tid = threadIdx.x;
  const int lane = tid & 63, wid = tid >> 6;
  const int m0 = blockIdx.y * 128, n0 = blockIdx.x * 128, bb = blockIdx.z;
  const int wm = wid >> 1, wn = wid & 1;
  const int fr = lane & 15, kg = lane >> 4;

  f32x4 acc[4][4];
#pragma unroll
  for (int m = 0; m < 4; ++m)
#pragma unroll
    for (int n = 0; n < 4; ++n) acc[m][n] = (f32x4){0.f, 0.f, 0.f, 0.f};

  const size_t wB = (size_t)bb * DDIM * DDIM;

  for (int k0 = 0; k0 < DDIM; k0 += 32) {
#pragma unroll
    for (int j = 0; j < 8; ++j) {          // wave w stages tile w, 8 chunks
      const int r0 = j * 16;
      const int row = r0 + (lane >> 2);
      const int s = lane & 3;
      const int ks = k0 + ((s ^ SWZ(row)) << 3);
      if (wid == 0)
        GLOAD16(Vh + (size_t)((m0 + row) * 4 + bb) * 1024 + ks, &sAh[r0][0]);
      else if (wid == 1)
        GLOAD16(Vl + (size_t)((m0 + row) * 4 + bb) * 1024 + ks, &sAl[r0][0]);
      else if (wid == 2)
        GLOAD16(Weh + wB + (size_t)(n0 + row) * 1024 + ks, &sBh[r0][0]);
      else
        GLOAD16(Wel + wB + (size_t)(n0 + row) * 1024 + ks, &sBl[r0][0]);
    }
    __syncthreads();

    short8v ah[4], al[4], bh[4], bl[4];
#pragma unroll
    for (int m = 0; m < 4; ++m) {
      const int row = wm * 64 + m * 16 + fr;
      const int so = (kg ^ SWZ(row)) << 3;
      ah[m] = *(const short8v*)&sAh[row][so];
      al[m] = *(const short8v*)&sAl[row][so];
    }
#pragma unroll
    for (int n = 0; n < 4; ++n) {
      const int col = wn * 64 + n * 16 + fr;
      const int so = (kg ^ SWZ(col)) << 3;
      bh[n] = *(const short8v*)&sBh[col][so];
      bl[n] = *(const short8v*)&sBl[col][so];
    }
#pragma unroll
    for (int m = 0; m < 4; ++m)
#pragma unroll
      for (int n = 0; n < 4; ++n) {
        acc[m][n] = __builtin_amdgcn_mfma_f32_16x16x32_bf16(ah[m], bh[n], acc[m][n], 0, 0, 0);
        acc[m][n] = __builtin_amdgcn_mfma_f32_16x16x32_bf16(ah[m], bl[n], acc[m][n], 0, 0, 0);
        acc[m][n] = __builtin_amdgcn_mfma_f32_16x16x32_bf16(al[m], bh[n], acc[m][n], 0, 0, 0);
      }
    __syncthreads();
  }

  float* Ob = Out + (size_t)bb * 1024;     // row t -> offset t*4096
#pragma unroll
  for (int m = 0; m < 4; ++m)
#pragma unroll
    for (int n = 0; n < 4; ++n) {
      const int col = n0 + wn * 64 + n * 16 + fr;
      const float bz = bias[col];
#pragma unroll
      for (int r = 0; r < 4; ++r) {
        const int row = m0 + wm * 64 + m * 16 + kg * 4 + r;
        Ob[(size_t)row * 4096 + col] = acc[m][n][r] + bz;
      }
    }
}

// ---------------------------------------------------------------------------
// Correlation partials: grid (64 bh, 16 seg), 256 threads = 4 waves.
// Head-major Qc/Kc -> each block streams contiguous 64KB q + 64KB k.
// Wave-private staging slices, no barriers in the t-loop.
// Record: 4096 c + 256 sums = 4352 floats (layout unchanged).
// ---------------------------------------------------------------------------
__global__ __launch_bounds__(256)
void corr_partial(const float* __restrict__ Qc, const float* __restrict__ Kc,
                  float* __restrict__ P)
{
  __shared__ float qs[4][16][64];    // 16 KB; reused as cbuf[64][64] after loop
  __shared__ float ks[4][16][64];    // 16 KB
  __shared__ float ssum[4][4][64];   // 4 KB: per-wave {Sq,Sk,Sq2,Sk2}
  const int bh  = blockIdx.x;
  const int seg = blockIdx.y;
  const int tid = threadIdx.x;
  const int wid = tid >> 6, lane = tid & 63;
  const float* qb = Qc + (size_t)bh * 262144;   // [4096][64]
  const float* kb = Kc + (size_t)bh * 262144;
  const int ty = lane >> 3;    // 0..7 -> d rows ty*8..+8
  const int tx = lane & 7;     // 0..7 -> e cols tx*8..+8
  const int rr = lane >> 4;    // staging row base 0..3
  const int cq = lane & 15;    // staging float4 col

  float acc[8][8];
#pragma unroll
  for (int i = 0; i < 8; ++i)
#pragma unroll
    for (int j = 0; j < 8; ++j) acc[i][j] = 0.f;
  float sQ[4]  = {0,0,0,0}, sK[4]  = {0,0,0,0};
  float sQ2[4] = {0,0,0,0}, sK2[4] = {0,0,0,0};

  for (int c = 0; c < 4; ++c) {      // wave handles 4 chunks of 16 t
    const int tbase = seg * 256 + wid * 64 + c * 16;
    float4 qv[4], kv[4];
#pragma unroll
    for (int i = 0; i < 4; ++i) {
      const size_t g = (size_t)(tbase + rr + i*4) * 64 + cq * 4;
      qv[i] = *(const float4*)&qb[g];
      kv[i] = *(const float4*)&kb[g];
    }
#pragma unroll
    for (int i = 0; i < 4; ++i) {
      const int row = rr + i*4;
      *(float4*)&qs[wid][row][cq*4] = qv[i];
      *(float4*)&ks[wid][row][cq*4] = kv[i];
      sQ[0] += qv[i].x; sQ[1] += qv[i].y; sQ[2] += qv[i].z; sQ[3] += qv[i].w;
      sK[0] += kv[i].x; sK[1] += kv[i].y; sK[2] += kv[i].z; sK[3] += kv[i].w;
      sQ2[0] = fmaf(qv[i].x, qv[i].x, sQ2[0]); sQ2[1] = fmaf(qv[i].y, qv[i].y, sQ2[1]);
      sQ2[2] = fmaf(qv[i].z, qv[i].z, sQ2[2]); sQ2[3] = fmaf(qv[i].w, qv[i].w, sQ2[3]);
      sK2[0] = fmaf(kv[i].x, kv[i].x, sK2[0]); sK2[1] = fmaf(kv[i].y, kv[i].y, sK2[1]);
      sK2[2] = fmaf(kv[i].z, kv[i].z, sK2[2]); sK2[3] = fmaf(kv[i].w, kv[i].w, sK2[3]);
    }
#pragma unroll 8
    for (int t = 0; t < 16; ++t) {
      const float4 qa  = *(const float4*)&qs[wid][t][ty*8];
      const float4 qb4 = *(const float4*)&qs[wid][t][ty*8+4];
      const float4 ka  = *(const float4*)&ks[wid][t][tx*8];
      const float4 kb4 = *(const float4*)&ks[wid][t][tx*8+4];
      const float av[8] = {qa.x, qa.y, qa.z, qa.w, qb4.x, qb4.y, qb4.z, qb4.w};
      const float bv[8] = {ka.x, ka.y, ka.z, ka.w, kb4.x, kb4.y, kb4.z, kb4.w};
#pragma unroll
      for (int i = 0; i < 8; ++i)
#pragma unroll
        for (int j = 0; j < 8; ++j)
          acc[i][j] = fmaf(av[i], bv[j], acc[i][j]);
    }
  }

  // per-wave sum reduce across lanes {cq, cq+16, cq+32, cq+48}
#pragma unroll
  for (int j = 0; j < 4; ++j) {
    sQ[j]  += __shfl_xor(sQ[j], 16, 64);  sQ[j]  += __shfl_xor(sQ[j], 32, 64);
    sK[j]  += __shfl_xor(sK[j], 16, 64);  sK[j]  += __shfl_xor(sK[j], 32, 64);
    sQ2[j] += __shfl_xor(sQ2[j], 16, 64); sQ2[j] += __shfl_xor(sQ2[j], 32, 64);
    sK2[j] += __shfl_xor(sK2[j], 16, 64); sK2[j] += __shfl_xor(sK2[j], 32, 64);
  }
  if (lane < 16) {
    float4 q4; q4.x = sQ[0];  q4.y = sQ[1];  q4.z = sQ[2];  q4.w = sQ[3];
    float4 k4; k4.x = sK[0];  k4.y = sK[1];  k4.z = sK[2];  k4.w = sK[3];
    float4 q2; q2.x = sQ2[0]; q2.y = sQ2[1]; q2.z = sQ2[2]; q2.w = sQ2[3];
    float4 k2; k2.x = sK2[0]; k2.y = sK2[1]; k2.z = sK2[2]; k2.w = sK2[3];
    *(float4*)&ssum[wid][0][lane*4] = q4;
    *(float4*)&ssum[wid][1][lane*4] = k4;
    *(float4*)&ssum[wid][2][lane*4] = q2;
    *(float4*)&ssum[wid][3][lane*4] = k2;
  }

  // cross-wave c reduction into cbuf (overlays qs; all staging reads done)
  float* cbuf = &qs[0][0][0];
  __syncthreads();
#pragma unroll
  for (int w = 0; w < 4; ++w) {
    if (wid == w) {
#pragma unroll
      for (int i = 0; i < 8; ++i) {
        float* p0 = &cbuf[(ty*8 + i) * 64 + tx*8];
        if (w == 0) {
          float4 o0, o1;
          o0.x = acc[i][0]; o0.y = acc[i][1]; o0.z = acc[i][2]; o0.w = acc[i][3];
          o1.x = acc[i][4]; o1.y = acc[i][5]; o1.z = acc[i][6]; o1.w = acc[i][7];
          *(float4*)p0 = o0; *(float4*)(p0 + 4) = o1;
        } else {
          float4 o0 = *(const float4*)p0, o1 = *(const float4*)(p0 + 4);
          o0.x += acc[i][0]; o0.y += acc[i][1]; o0.z += acc[i][2]; o0.w += acc[i][3];
          o1.x += acc[i][4]; o1.y += acc[i][5]; o1.z += acc[i][6]; o1.w += acc[i][7];
          *(float4*)p0 = o0; *(float4*)(p0 + 4) = o1;
        }
      }
    }
    __syncthreads();
  }

  // write record: 4096 c + 256 sums
  float* Pb = P + (size_t)(bh * 16 + seg) * 4352;
#pragma unroll
  for (int i = 0; i < 4; ++i)
    ((float4*)Pb)[tid + 256*i] = ((const float4*)cbuf)[tid + 256*i];
  {
    const int comp = tid >> 6, d = tid & 63;
    Pb[4096 + tid] = ssum[0][comp][d] + ssum[1][comp][d] +
                     ssum[2][comp][d] + ssum[3][comp][d];
  }
}

// ---------------------------------------------------------------------------
// Finalize: sum 16 segment partials; corr = clip((c-SqSk/T)/sqrt(sx*sy),-1,1)
// grid (64 bh, 4 quarters) for 4x the r4 parallelism; sums re-read per block.
// ---------------------------------------------------------------------------
__global__ __launch_bounds__(256)
void corr_finalize(const float* __restrict__ P, float* __restrict__ corr)
{
  __shared__ float fin[4][64];
  const int bh = blockIdx.x, qtr = blockIdx.y;
  const int tid = threadIdx.x;
  const float* Pb = P + (size_t)bh * 16 * 4352;

  float s = 0.f;
  for (int seg = 0; seg < 16; ++seg) s += Pb[(size_t)seg*4352 + 4096 + tid];
  fin[tid >> 6][tid & 63] = s;

  float cacc[4] = {0.f, 0.f, 0.f, 0.f};
  for (int seg = 0; seg < 16; ++seg) {
#pragma unroll
    for (int i = 0; i < 4; ++i)
      cacc[i] += Pb[(size_t)seg*4352 + qtr*1024 + tid + i*256];
  }
  __syncthreads();

  const float invT = 1.0f / (float)TDIM;
#pragma unroll
  for (int i = 0; i < 4; ++i) {
    const int f = qtr*1024 + tid + i*256;
    const int d = f >> 6, e = f & 63;
    const float sq = fin[0][d], sk = fin[1][e];
    const float sq2 = fin[2][d], sk2 = fin[3][e];
    const float cc = cacc[i] - sq * sk * invT;
    const float sx = sq2 - sq * sq * invT;
    const float sy = sk2 - sk * sk * invT;
    float v = cc / sqrtf(sx * sy);
    v = fminf(1.f, fmaxf(-1.f, v));
    corr[(size_t)bh * 4096 + f] = v;
  }
}

// ---------------------------------------------------------------------------
// Weff_b[n][h*64+d] = sum_e corr[b,h][d][e] * Wout[n][h*64+e]  (fp32)
// ---------------------------------------------------------------------------
__global__ __launch_bounds__(256)
void weff_kernel(const float* __restrict__ corr, const float* __restrict__ Wout,
                 float* __restrict__ Weff)
{
  __shared__ float cs[64][64];
  __shared__ float ws[128][64];
  const int bh = blockIdx.x;
  const int b = bh >> 4, h = bh & 15;
  const int n0 = blockIdx.y * 128;
  const int tid = threadIdx.x;

  const float* cb = corr + (size_t)bh * 4096;
  float4* csv = (float4*)&cs[0][0];
#pragma unroll
  for (int i = 0; i < 4; ++i)
    csv[tid + 256*i] = ((const float4*)cb)[tid + 256*i];

  const int wr = tid >> 1, wh = (tid & 1) * 32;
  const float* wrow = Wout + (size_t)(n0 + wr) * DDIM + h * HD + wh;
#pragma unroll
  for (int i = 0; i < 8; ++i)
    *(float4*)&ws[wr][wh + i*4] = *(const float4*)&wrow[i*4];
  __syncthreads();

  const int ni = (tid >> 3) * 4;
  const int di = (tid & 7) * 8;
  float acc[4][8];
#pragma unroll
  for (int i = 0; i < 4; ++i)
#pragma unroll
    for (int j = 0; j < 8; ++j) acc[i][j] = 0.f;

  for (int e = 0; e < 64; ++e) {
    float wv[4], cv[8];
#pragma unroll
    for (int i = 0; i < 4; ++i) wv[i] = ws[ni + i][e];
#pragma unroll
    for (int j = 0; j < 8; ++j) cv[j] = cs[di + j][e];
#pragma unroll
    for (int i = 0; i < 4; ++i)
#pragma unroll
      for (int j = 0; j < 8; ++j)
        acc[i][j] = fmaf(wv[i], cv[j], acc[i][j]);
  }

  float* Wb = Weff + (size_t)b * DDIM * DDIM + h * HD;
#pragma unroll
  for (int i = 0; i < 4; ++i) {
    float4 o0, o1;
    o0.x = acc[i][0]; o0.y = acc[i][1]; o0.z = acc[i][2]; o0.w = acc[i][3];
    o1.x = acc[i][4]; o1.y = acc[i][5]; o1.z = acc[i][6]; o1.w = acc[i][7];
    *(float4*)&Wb[(size_t)(n0 + ni + i) * DDIM + di]     = o0;
    *(float4*)&Wb[(size_t)(n0 + ni + i) * DDIM + di + 4] = o1;
  }
}

// ---------------------------------------------------------------------------
extern "C" void kernel_launch(void* const* d_in, const int* in_sizes, int n_in,
                              void* d_out, int out_size, void* d_ws, size_t ws_size,
                              hipStream_t stream)
{
  (void)in_sizes; (void)n_in; (void)out_size; (void)ws_size;
  const float* x    = (const float*)d_in[0];
  const float* Wqkv = (const float*)d_in[1];
  const float* bqkv = (const float*)d_in[2];
  const float* Wout = (const float*)d_in[3];
  const float* bout = (const float*)d_in[4];
  float* out = (float*)d_out;

  // ws layout (bytes), total 236,978,176 B = 226.0 MiB (== proven size)
  //  [0,64M)    Qc fp32 [64 bh][4096 t][64 d]   (head-major)
  //  [64M,128M) Kc fp32 [64 bh][4096 t][64 d]
  //  [+32M+32M) Vh, Vl bf16 [16384][1024]
  //  [+1M)      corr fp32 [64][64][64]
  //  R1 17.0M   phase A: Wqh/Wql (12.6M) -> phase B: P (17.0M) -> phase C: Weff fp32 (16M)
  //  R2 16M     Weh/Wel bf16 [4][1024][1024]
  char* w = (char*)d_ws;
  float*  Qc    = (float*)w;   w += (size_t)67108864;
  float*  Kc    = (float*)w;   w += (size_t)67108864;
  ushort* Vh    = (ushort*)w;  w += (size_t)33554432;
  ushort* Vl    = (ushort*)w;  w += (size_t)33554432;
  float*  corrB = (float*)w;   w += (size_t)1048576;
  char* R1 = w;                w += (size_t)17825792;
  char* R2 = w;
  ushort* Wqh   = (ushort*)R1;
  ushort* Wql   = Wqh + (size_t)3145728;
  float*  P     = (float*)R1;
  float*  WeffF = (float*)R1;
  ushort* Weh   = (ushort*)R2;
  ushort* Wel   = Weh + (size_t)4194304;

  // 1) split Wqkv -> bf16 hi/lo
  split_f32<<<dim3(1024), 256, 0, stream>>>(Wqkv, Wqh, Wql, 786432);
  // 2) qkv GEMM: q,k -> head-major fp32 Qc/Kc; v -> bf16 Vh/Vl
  gemm1_mfma<<<dim3(24, 128), 256, 0, stream>>>(x, Wqh, Wql, bqkv, Qc, Kc, Vh, Vl);
  // 3) correlation partials (P overwrites Wq splits - dead after GEMM1)
  corr_partial<<<dim3(64, 16), 256, 0, stream>>>(Qc, Kc, P);
  // 4) finalize corr
  corr_finalize<<<dim3(64, 4), 256, 0, stream>>>(P, corrB);
  // 5) Weff_b = fold(corr_b, Wout) fp32 (overwrites P - dead after finalize)
  weff_kernel<<<dim3(64, 8), 256, 0, stream>>>(corrB, Wout, WeffF);
  // 6) split Weff -> bf16 hi/lo
  split_f32<<<dim3(1024), 256, 0, stream>>>(WeffF, Weh, Wel, 1048576);
  // 7) out = v @ Weff_b^T + bout (batched over b)
  gemm2_mfma<<<dim3(8, 32, 4), 256, 0, stream>>>(Vh, Vl, Weh, Wel, bout, out);
}

// Round 6
// 638.591 us; speedup vs baseline: 2.6845x; 1.0299x over previous
//
#include <hip/hip_runtime.h>
#include <hip/hip_bf16.h>

// Problem constants (fixed by setup_inputs)
#define TDIM 4096
#define BDIM 4
#define DDIM 1024
#define HDIM 16
#define HD   64
#define MDIM (TDIM * BDIM)      // 16384 rows (t,b)

typedef __attribute__((ext_vector_type(8))) short short8v;  // 8 bf16 bits = 4 VGPR
typedef __attribute__((ext_vector_type(4))) float f32x4;

__device__ __forceinline__ ushort f2bfu(float f) {
  union { __hip_bfloat16 h; ushort u; } c;
  c.h = __float2bfloat16(f);
  return c.u;
}
__device__ __forceinline__ float bfu2f(ushort u) {
  union { ushort u; __hip_bfloat16 h; } c;
  c.u = u;
  return __bfloat162float(c.h);
}

// async global->LDS, 16B per lane; LDS dest = wave-uniform base + lane*16
#define GLOAD16(gp, lp) __builtin_amdgcn_global_load_lds( \
    (const __attribute__((address_space(1))) void*)(gp),  \
    (__attribute__((address_space(3))) void*)(lp), 16, 0, 0)

// LDS swizzle: g(row) = (row>>1)&3. Bank quad = 4*(row&1) + (slot^g(row))
// is bijective over 8 consecutive rows -> 2 lanes/quad on ds_read_b128 (free).
// Verified r4: SQ_LDS_BANK_CONFLICT 2.5e7 -> 0.
#define SWZ(row) (((row) >> 1) & 3)

// ---------------------------------------------------------------------------
// split fp32 -> bf16 hi/lo arrays (hi = bf16(x), lo = bf16(x - hi))
// ---------------------------------------------------------------------------
__global__ __launch_bounds__(256)
void split_f32(const float* __restrict__ in, ushort* __restrict__ hi,
               ushort* __restrict__ lo, int n4)
{
  int i = blockIdx.x * blockDim.x + threadIdx.x;
  const int stride = gridDim.x * blockDim.x;
  for (; i < n4; i += stride) {
    const float4 v = ((const float4*)in)[i];
    ushort4 h, l;
    h.x = f2bfu(v.x); l.x = f2bfu(v.x - bfu2f(h.x));
    h.y = f2bfu(v.y); l.y = f2bfu(v.y - bfu2f(h.y));
    h.z = f2bfu(v.z); l.z = f2bfu(v.z - bfu2f(h.z));
    h.w = f2bfu(v.w); l.w = f2bfu(v.w - bfu2f(h.w));
    ((ushort4*)hi)[i] = h;
    ((ushort4*)lo)[i] = l;
  }
}

// ---------------------------------------------------------------------------
// GEMM1: qkv = x @ Wqkv^T + bqkv via split-bf16 3-MFMA.
// A = x fp32 (reg-staged, split on the fly), B = pre-split Wh/Wl (gload_lds).
// Output: q -> Qc[bh][t][64] fp32 (head-major); k -> Kc; v -> bf16 hi/lo V.
// 128x128 tile, BK=32, 4 waves (2x2), each wave 4x4 frags of 16x16x32.
// ---------------------------------------------------------------------------
__global__ __launch_bounds__(256, 2)
void gemm1_mfma(const float* __restrict__ X, const ushort* __restrict__ Wh,
                const ushort* __restrict__ Wl, const float* __restrict__ bias,
                float* __restrict__ Qc, float* __restrict__ Kc,
                ushort* __restrict__ Vh, ushort* __restrict__ Vl)
{
  __shared__ ushort sAh[128][32], sAl[128][32], sBh[128][32], sBl[128][32];
  const int tid = threadIdx.x;
  const int lane = tid & 63, wid = tid >> 6;
  const int m0 = blockIdx.y * 128, n0 = blockIdx.x * 128;
  const int ar = tid >> 3, aq = tid & 7;       // A staging: row base, float4 slot
  const int wm = wid >> 1, wn = wid & 1;       // wave grid 2x2
  const int fr = lane & 15, kg = lane >> 4;    // frag row/col, k-group

  f32x4 acc[4][4];
#pragma unroll
  for (int m = 0; m < 4; ++m)
#pragma unroll
    for (int n = 0; n < 4; ++n) acc[m][n] = (f32x4){0.f, 0.f, 0.f, 0.f};

  for (int k0 = 0; k0 < DDIM; k0 += 32) {
    // ---- stage: A fp32 loads first, then B gload_lds (latency overlap) ----
    float4 av[4];
#pragma unroll
    for (int i = 0; i < 4; ++i)
      av[i] = *(const float4*)&X[(size_t)(m0 + ar + i * 32) * DDIM + k0 + aq * 4];
#pragma unroll
    for (int j = 0; j < 4; ++j) {
      const int c = wid * 4 + j;                 // 16 chunks: 8 Bh + 8 Bl
      const int r0 = (c & 7) * 16;
      const int row = r0 + (lane >> 2);
      const int s = lane & 3;
      const size_t goff = (size_t)(n0 + row) * DDIM + k0 + ((s ^ SWZ(row)) << 3);
      if (c < 8) GLOAD16(Wh + goff, &sBh[r0][0]);
      else       GLOAD16(Wl + goff, &sBl[r0][0]);
    }
#pragma unroll
    for (int i = 0; i < 4; ++i) {
      const int row = ar + i * 32;
      const int sl = (((aq >> 1) ^ SWZ(row)) << 3) + ((aq & 1) << 2);
      ushort4 hv, lv;
      hv.x = f2bfu(av[i].x); lv.x = f2bfu(av[i].x - bfu2f(hv.x));
      hv.y = f2bfu(av[i].y); lv.y = f2bfu(av[i].y - bfu2f(hv.y));
      hv.z = f2bfu(av[i].z); lv.z = f2bfu(av[i].z - bfu2f(hv.z));
      hv.w = f2bfu(av[i].w); lv.w = f2bfu(av[i].w - bfu2f(hv.w));
      *(ushort4*)&sAh[row][sl] = hv;
      *(ushort4*)&sAl[row][sl] = lv;
    }
    __syncthreads();   // drains vmcnt (gload_lds) + lgkm (ds_write)

    // ---- compute: 16 ds_read_b128 + 48 MFMA per wave ----
    short8v ah[4], al[4], bh[4], bl[4];
#pragma unroll
    for (int m = 0; m < 4; ++m) {
      const int row = wm * 64 + m * 16 + fr;
      const int so = (kg ^ SWZ(row)) << 3;
      ah[m] = *(const short8v*)&sAh[row][so];
      al[m] = *(const short8v*)&sAl[row][so];
    }
#pragma unroll
    for (int n = 0; n < 4; ++n) {
      const int col = wn * 64 + n * 16 + fr;
      const int so = (kg ^ SWZ(col)) << 3;
      bh[n] = *(const short8v*)&sBh[col][so];
      bl[n] = *(const short8v*)&sBl[col][so];
    }
#pragma unroll
    for (int m = 0; m < 4; ++m)
#pragma unroll
      for (int n = 0; n < 4; ++n) {
        acc[m][n] = __builtin_amdgcn_mfma_f32_16x16x32_bf16(ah[m], bh[n], acc[m][n], 0, 0, 0);
        acc[m][n] = __builtin_amdgcn_mfma_f32_16x16x32_bf16(ah[m], bl[n], acc[m][n], 0, 0, 0);
        acc[m][n] = __builtin_amdgcn_mfma_f32_16x16x32_bf16(al[m], bh[n], acc[m][n], 0, 0, 0);
      }
    __syncthreads();   // all reads done before next stage overwrites
  }

  // ---- epilogue: C/D layout col=lane&15, row=(lane>>4)*4+reg (m89) ----
  const int region = n0 >> 10;   // 0=q, 1=k, 2=v (128-tiles never straddle)
#pragma unroll
  for (int m = 0; m < 4; ++m)
#pragma unroll
    for (int n = 0; n < 4; ++n) {
      const int col = n0 + wn * 64 + n * 16 + fr;
      const float bz = bias[col];
      const int cc = col & 1023;
      const int hh = cc >> 6, dd = cc & 63;
#pragma unroll
      for (int r = 0; r < 4; ++r) {
        const int row = m0 + wm * 64 + m * 16 + kg * 4 + r;
        const float v = acc[m][n][r] + bz;
        const int t = row >> 2, b = row & 3;     // rows are (t,b) interleaved
        const size_t ho = (((size_t)(b * 16 + hh)) * 4096 + t) * 64 + dd;
        if (region == 0)      Qc[ho] = v;
        else if (region == 1) Kc[ho] = v;
        else {
          const size_t o = (size_t)row * 1024 + cc;
          const ushort h2 = f2bfu(v);
          Vh[o] = h2;
          Vl[o] = f2bfu(v - bfu2f(h2));
        }
      }
    }
}

// ---------------------------------------------------------------------------
// GEMM2 (batched over b): out[t,b,:] = v[t,b,:] @ Weff_b^T + bout.
// r6: BM=64, BN=128 -> grid (8, 64, 4) = 2048 blocks (2x of r5's 1024; fixes
// ~1.5-dispatch-round tail quantization). B (32 MB) is L3-resident across its
// m-tile re-reads. Same verified 2-barrier template, SWZ, epilogue formula.
// 4 waves 2x2: wave-tile 32x64 -> 2 m-frags x 4 n-frags, 24 MFMA/wave/iter.
// ---------------------------------------------------------------------------
__global__ __launch_bounds__(256, 2)
void gemm2_mfma(const ushort* __restrict__ Vh, const ushort* __restrict__ Vl,
                const ushort* __restrict__ Weh, const ushort* __restrict__ Wel,
                const float* __restrict__ bias, float* __restrict__ Out)
{
  __shared__ ushort sAh[64][32], sAl[64][32], sBh[128][32], sBl[128][32];
  const int tid = threadIdx.x;
  const int lane = tid & 63, wid = tid >> 6;
  const int m0 = blockIdx.y * 64, n0 = blockIdx.x * 128, bb = blockIdx.z;
  const int wm = wid >> 1, wn = wid & 1;
  const int fr = lane & 15, kg = lane >> 4;

  f32x4 acc[2][4];
#pragma unroll
  for (int m = 0; m < 2; ++m)
#pragma unroll
    for (int n = 0; n < 4; ++n) acc[m][n] = (f32x4){0.f, 0.f, 0.f, 0.f};

  const size_t wB = (size_t)bb * DDIM * DDIM;

  for (int k0 = 0; k0 < DDIM; k0 += 32) {
    // 24 staging chunks of 16 rows x 1KB: Ah c0..3, Al c4..7, Bh c8..15,
    // Bl c16..23. Wave w issues chunks w*6..w*6+5 (uniform LDS base per chunk).
#pragma unroll
    for (int j = 0; j < 6; ++j) {
      const int c = wid * 6 + j;
      const int rl = lane >> 2, s = lane & 3;
      if (c < 8) {
        const int r0 = (c & 3) * 16;
        const int row = r0 + rl;
        const size_t g = (size_t)((m0 + row) * 4 + bb) * 1024 + k0 + ((s ^ SWZ(row)) << 3);
        if (c < 4) GLOAD16(Vh + g, &sAh[r0][0]);
        else       GLOAD16(Vl + g, &sAl[r0][0]);
      } else {
        const int r0 = ((c - 8) & 7) * 16;
        const int row = r0 + rl;
        const size_t g = wB + (size_t)(n0 + row) * 1024 + k0 + ((s ^ SWZ(row)) << 3);
        if (c < 16) GLOAD16(Weh + g, &sBh[r0][0]);
        else        GLOAD16(Wel + g, &sBl[r0][0]);
      }
    }
    __syncthreads();

    short8v ah[2], al[2], bh[4], bl[4];
#pragma unroll
    for (int m = 0; m < 2; ++m) {
      const int row = wm * 32 + m * 16 + fr;
      const int so = (kg ^ SWZ(row)) << 3;
      ah[m] = *(const short8v*)&sAh[row][so];
      al[m] = *(const short8v*)&sAl[row][so];
    }
#pragma unroll
    for (int n = 0; n < 4; ++n) {
      const int col = wn * 64 + n * 16 + fr;
      const int so = (kg ^ SWZ(col)) << 3;
      bh[n] = *(const short8v*)&sBh[col][so];
      bl[n] = *(const short8v*)&sBl[col][so];
    }
#pragma unroll
    for (int m = 0; m < 2; ++m)
#pragma unroll
      for (int n = 0; n < 4; ++n) {
        acc[m][n] = __builtin_amdgcn_mfma_f32_16x16x32_bf16(ah[m], bh[n], acc[m][n], 0, 0, 0);
        acc[m][n] = __builtin_amdgcn_mfma_f32_16x16x32_bf16(ah[m], bl[n], acc[m][n], 0, 0, 0);
        acc[m][n] = __builtin_amdgcn_mfma_f32_16x16x32_bf16(al[m], bh[n], acc[m][n], 0, 0, 0);
      }
    __syncthreads();
  }

  float* Ob = Out + (size_t)bb * 1024;     // row t -> offset t*4096
#pragma unroll
  for (int m = 0; m < 2; ++m)
#pragma unroll
    for (int n = 0; n < 4; ++n) {
      const int col = n0 + wn * 64 + n * 16 + fr;
      const float bz = bias[col];
#pragma unroll
      for (int r = 0; r < 4; ++r) {
        const int row = m0 + wm * 32 + m * 16 + kg * 4 + r;
        Ob[(size_t)row * 4096 + col] = acc[m][n][r] + bz;
      }
    }
}

// ---------------------------------------------------------------------------
// Correlation partials: grid (64 bh, 16 seg), 256 threads = 4 waves.
// Head-major Qc/Kc -> each block streams contiguous 64KB q + 64KB k.
// Wave-private staging slices, no barriers in the t-loop.
// Record: 4096 c + 256 sums = 4352 floats (layout unchanged).
// ---------------------------------------------------------------------------
__global__ __launch_bounds__(256)
void corr_partial(const float* __restrict__ Qc, const float* __restrict__ Kc,
                  float* __restrict__ P)
{
  __shared__ float qs[4][16][64];    // 16 KB; reused as cbuf[64][64] after loop
  __shared__ float ks[4][16][64];    // 16 KB
  __shared__ float ssum[4][4][64];   // 4 KB: per-wave {Sq,Sk,Sq2,Sk2}
  const int bh  = blockIdx.x;
  const int seg = blockIdx.y;
  const int tid = threadIdx.x;
  const int wid = tid >> 6, lane = tid & 63;
  const float* qb = Qc + (size_t)bh * 262144;   // [4096][64]
  const float* kb = Kc + (size_t)bh * 262144;
  const int ty = lane >> 3;    // 0..7 -> d rows ty*8..+8
  const int tx = lane & 7;     // 0..7 -> e cols tx*8..+8
  const int rr = lane >> 4;    // staging row base 0..3
  const int cq = lane & 15;    // staging float4 col

  float acc[8][8];
#pragma unroll
  for (int i = 0; i < 8; ++i)
#pragma unroll
    for (int j = 0; j < 8; ++j) acc[i][j] = 0.f;
  float sQ[4]  = {0,0,0,0}, sK[4]  = {0,0,0,0};
  float sQ2[4] = {0,0,0,0}, sK2[4] = {0,0,0,0};

  for (int c = 0; c < 4; ++c) {      // wave handles 4 chunks of 16 t
    const int tbase = seg * 256 + wid * 64 + c * 16;
    float4 qv[4], kv[4];
#pragma unroll
    for (int i = 0; i < 4; ++i) {
      const size_t g = (size_t)(tbase + rr + i*4) * 64 + cq * 4;
      qv[i] = *(const float4*)&qb[g];
      kv[i] = *(const float4*)&kb[g];
    }
#pragma unroll
    for (int i = 0; i < 4; ++i) {
      const int row = rr + i*4;
      *(float4*)&qs[wid][row][cq*4] = qv[i];
      *(float4*)&ks[wid][row][cq*4] = kv[i];
      sQ[0] += qv[i].x; sQ[1] += qv[i].y; sQ[2] += qv[i].z; sQ[3] += qv[i].w;
      sK[0] += kv[i].x; sK[1] += kv[i].y; sK[2] += kv[i].z; sK[3] += kv[i].w;
      sQ2[0] = fmaf(qv[i].x, qv[i].x, sQ2[0]); sQ2[1] = fmaf(qv[i].y, qv[i].y, sQ2[1]);
      sQ2[2] = fmaf(qv[i].z, qv[i].z, sQ2[2]); sQ2[3] = fmaf(qv[i].w, qv[i].w, sQ2[3]);
      sK2[0] = fmaf(kv[i].x, kv[i].x, sK2[0]); sK2[1] = fmaf(kv[i].y, kv[i].y, sK2[1]);
      sK2[2] = fmaf(kv[i].z, kv[i].z, sK2[2]); sK2[3] = fmaf(kv[i].w, kv[i].w, sK2[3]);
    }
#pragma unroll 8
    for (int t = 0; t < 16; ++t) {
      const float4 qa  = *(const float4*)&qs[wid][t][ty*8];
      const float4 qb4 = *(const float4*)&qs[wid][t][ty*8+4];
      const float4 ka  = *(const float4*)&ks[wid][t][tx*8];
      const float4 kb4 = *(const float4*)&ks[wid][t][tx*8+4];
      const float av[8] = {qa.x, qa.y, qa.z, qa.w, qb4.x, qb4.y, qb4.z, qb4.w};
      const float bv[8] = {ka.x, ka.y, ka.z, ka.w, kb4.x, kb4.y, kb4.z, kb4.w};
#pragma unroll
      for (int i = 0; i < 8; ++i)
#pragma unroll
        for (int j = 0; j < 8; ++j)
          acc[i][j] = fmaf(av[i], bv[j], acc[i][j]);
    }
  }

  // per-wave sum reduce across lanes {cq, cq+16, cq+32, cq+48}
#pragma unroll
  for (int j = 0; j < 4; ++j) {
    sQ[j]  += __shfl_xor(sQ[j], 16, 64);  sQ[j]  += __shfl_xor(sQ[j], 32, 64);
    sK[j]  += __shfl_xor(sK[j], 16, 64);  sK[j]  += __shfl_xor(sK[j], 32, 64);
    sQ2[j] += __shfl_xor(sQ2[j], 16, 64); sQ2[j] += __shfl_xor(sQ2[j], 32, 64);
    sK2[j] += __shfl_xor(sK2[j], 16, 64); sK2[j] += __shfl_xor(sK2[j], 32, 64);
  }
  if (lane < 16) {
    float4 q4; q4.x = sQ[0];  q4.y = sQ[1];  q4.z = sQ[2];  q4.w = sQ[3];
    float4 k4; k4.x = sK[0];  k4.y = sK[1];  k4.z = sK[2];  k4.w = sK[3];
    float4 q2; q2.x = sQ2[0]; q2.y = sQ2[1]; q2.z = sQ2[2]; q2.w = sQ2[3];
    float4 k2; k2.x = sK2[0]; k2.y = sK2[1]; k2.z = sK2[2]; k2.w = sK2[3];
    *(float4*)&ssum[wid][0][lane*4] = q4;
    *(float4*)&ssum[wid][1][lane*4] = k4;
    *(float4*)&ssum[wid][2][lane*4] = q2;
    *(float4*)&ssum[wid][3][lane*4] = k2;
  }

  // cross-wave c reduction into cbuf (overlays qs; all staging reads done)
  float* cbuf = &qs[0][0][0];
  __syncthreads();
#pragma unroll
  for (int w = 0; w < 4; ++w) {
    if (wid == w) {
#pragma unroll
      for (int i = 0; i < 8; ++i) {
        float* p0 = &cbuf[(ty*8 + i) * 64 + tx*8];
        if (w == 0) {
          float4 o0, o1;
          o0.x = acc[i][0]; o0.y = acc[i][1]; o0.z = acc[i][2]; o0.w = acc[i][3];
          o1.x = acc[i][4]; o1.y = acc[i][5]; o1.z = acc[i][6]; o1.w = acc[i][7];
          *(float4*)p0 = o0; *(float4*)(p0 + 4) = o1;
        } else {
          float4 o0 = *(const float4*)p0, o1 = *(const float4*)(p0 + 4);
          o0.x += acc[i][0]; o0.y += acc[i][1]; o0.z += acc[i][2]; o0.w += acc[i][3];
          o1.x += acc[i][4]; o1.y += acc[i][5]; o1.z += acc[i][6]; o1.w += acc[i][7];
          *(float4*)p0 = o0; *(float4*)(p0 + 4) = o1;
        }
      }
    }
    __syncthreads();
  }

  // write record: 4096 c + 256 sums
  float* Pb = P + (size_t)(bh * 16 + seg) * 4352;
#pragma unroll
  for (int i = 0; i < 4; ++i)
    ((float4*)Pb)[tid + 256*i] = ((const float4*)cbuf)[tid + 256*i];
  {
    const int comp = tid >> 6, d = tid & 63;
    Pb[4096 + tid] = ssum[0][comp][d] + ssum[1][comp][d] +
                     ssum[2][comp][d] + ssum[3][comp][d];
  }
}

// ---------------------------------------------------------------------------
// Finalize: sum 16 segment partials; corr = clip((c-SqSk/T)/sqrt(sx*sy),-1,1)
// grid (64 bh, 4 quarters); sums re-read per block.
// ---------------------------------------------------------------------------
__global__ __launch_bounds__(256)
void corr_finalize(const float* __restrict__ P, float* __restrict__ corr)
{
  __shared__ float fin[4][64];
  const int bh = blockIdx.x, qtr = blockIdx.y;
  const int tid = threadIdx.x;
  const float* Pb = P + (size_t)bh * 16 * 4352;

  float s = 0.f;
  for (int seg = 0; seg < 16; ++seg) s += Pb[(size_t)seg*4352 + 4096 + tid];
  fin[tid >> 6][tid & 63] = s;

  float cacc[4] = {0.f, 0.f, 0.f, 0.f};
  for (int seg = 0; seg < 16; ++seg) {
#pragma unroll
    for (int i = 0; i < 4; ++i)
      cacc[i] += Pb[(size_t)seg*4352 + qtr*1024 + tid + i*256];
  }
  __syncthreads();

  const float invT = 1.0f / (float)TDIM;
#pragma unroll
  for (int i = 0; i < 4; ++i) {
    const int f = qtr*1024 + tid + i*256;
    const int d = f >> 6, e = f & 63;
    const float sq = fin[0][d], sk = fin[1][e];
    const float sq2 = fin[2][d], sk2 = fin[3][e];
    const float cc = cacc[i] - sq * sk * invT;
    const float sx = sq2 - sq * sq * invT;
    const float sy = sk2 - sk * sk * invT;
    float v = cc / sqrtf(sx * sy);
    v = fminf(1.f, fmaxf(-1.f, v));
    corr[(size_t)bh * 4096 + f] = v;
  }
}

// ---------------------------------------------------------------------------
// Weff_b[n][h*64+d] = sum_e corr[b,h][d][e] * Wout[n][h*64+e]
// r6: writes bf16 hi/lo directly (fuses the old split_f32(Weff) pass).
// ---------------------------------------------------------------------------
__global__ __launch_bounds__(256)
void weff_kernel(const float* __restrict__ corr, const float* __restrict__ Wout,
                 ushort* __restrict__ Weh, ushort* __restrict__ Wel)
{
  __shared__ float cs[64][64];
  __shared__ float ws[128][64];
  const int bh = blockIdx.x;
  const int b = bh >> 4, h = bh & 15;
  const int n0 = blockIdx.y * 128;
  const int tid = threadIdx.x;

  const float* cb = corr + (size_t)bh * 4096;
  float4* csv = (float4*)&cs[0][0];
#pragma unroll
  for (int i = 0; i < 4; ++i)
    csv[tid + 256*i] = ((const float4*)cb)[tid + 256*i];

  const int wr = tid >> 1, wh = (tid & 1) * 32;
  const float* wrow = Wout + (size_t)(n0 + wr) * DDIM + h * HD + wh;
#pragma unroll
  for (int i = 0; i < 8; ++i)
    *(float4*)&ws[wr][wh + i*4] = *(const float4*)&wrow[i*4];
  __syncthreads();

  const int ni = (tid >> 3) * 4;
  const int di = (tid & 7) * 8;
  float acc[4][8];
#pragma unroll
  for (int i = 0; i < 4; ++i)
#pragma unroll
    for (int j = 0; j < 8; ++j) acc[i][j] = 0.f;

  for (int e = 0; e < 64; ++e) {
    float wv[4], cv[8];
#pragma unroll
    for (int i = 0; i < 4; ++i) wv[i] = ws[ni + i][e];
#pragma unroll
    for (int j = 0; j < 8; ++j) cv[j] = cs[di + j][e];
#pragma unroll
    for (int i = 0; i < 4; ++i)
#pragma unroll
      for (int j = 0; j < 8; ++j)
        acc[i][j] = fmaf(wv[i], cv[j], acc[i][j]);
  }

  const size_t base = (size_t)b * DDIM * DDIM + h * HD;
#pragma unroll
  for (int i = 0; i < 4; ++i) {
    ushort4 h0, l0, h1, l1;
    h0.x = f2bfu(acc[i][0]); l0.x = f2bfu(acc[i][0] - bfu2f(h0.x));
    h0.y = f2bfu(acc[i][1]); l0.y = f2bfu(acc[i][1] - bfu2f(h0.y));
    h0.z = f2bfu(acc[i][2]); l0.z = f2bfu(acc[i][2] - bfu2f(h0.z));
    h0.w = f2bfu(acc[i][3]); l0.w = f2bfu(acc[i][3] - bfu2f(h0.w));
    h1.x = f2bfu(acc[i][4]); l1.x = f2bfu(acc[i][4] - bfu2f(h1.x));
    h1.y = f2bfu(acc[i][5]); l1.y = f2bfu(acc[i][5] - bfu2f(h1.y));
    h1.z = f2bfu(acc[i][6]); l1.z = f2bfu(acc[i][6] - bfu2f(h1.z));
    h1.w = f2bfu(acc[i][7]); l1.w = f2bfu(acc[i][7] - bfu2f(h1.w));
    const size_t o = base + (size_t)(n0 + ni + i) * DDIM + di;
    *(ushort4*)&Weh[o]     = h0;
    *(ushort4*)&Weh[o + 4] = h1;
    *(ushort4*)&Wel[o]     = l0;
    *(ushort4*)&Wel[o + 4] = l1;
  }
}

// ---------------------------------------------------------------------------
extern "C" void kernel_launch(void* const* d_in, const int* in_sizes, int n_in,
                              void* d_out, int out_size, void* d_ws, size_t ws_size,
                              hipStream_t stream)
{
  (void)in_sizes; (void)n_in; (void)out_size; (void)ws_size;
  const float* x    = (const float*)d_in[0];
  const float* Wqkv = (const float*)d_in[1];
  const float* bqkv = (const float*)d_in[2];
  const float* Wout = (const float*)d_in[3];
  const float* bout = (const float*)d_in[4];
  float* out = (float*)d_out;

  // ws layout (bytes), total 220,200,960 B = 210.0 MiB
  //  [0,64M)    Qc fp32 [64 bh][4096 t][64 d]   (head-major)
  //  [64M,128M) Kc fp32 [64 bh][4096 t][64 d]
  //  [+32M+32M) Vh, Vl bf16 [16384][1024]
  //  [+1M)      corr fp32 [64][64][64]
  //  R1 17.0M   phase A: Wqh/Wql (12.6M) -> phase B: P (17.0M)
  //  R2 16M     Weh/Wel bf16 [4][1024][1024]
  char* w = (char*)d_ws;
  float*  Qc    = (float*)w;   w += (size_t)67108864;
  float*  Kc    = (float*)w;   w += (size_t)67108864;
  ushort* Vh    = (ushort*)w;  w += (size_t)33554432;
  ushort* Vl    = (ushort*)w;  w += (size_t)33554432;
  float*  corrB = (float*)w;   w += (size_t)1048576;
  char* R1 = w;                w += (size_t)17825792;
  char* R2 = w;
  ushort* Wqh   = (ushort*)R1;
  ushort* Wql   = Wqh + (size_t)3145728;
  float*  P     = (float*)R1;
  ushort* Weh   = (ushort*)R2;
  ushort* Wel   = Weh + (size_t)4194304;

  // 1) split Wqkv -> bf16 hi/lo
  split_f32<<<dim3(1024), 256, 0, stream>>>(Wqkv, Wqh, Wql, 786432);
  // 2) qkv GEMM: q,k -> head-major fp32 Qc/Kc; v -> bf16 Vh/Vl
  gemm1_mfma<<<dim3(24, 128), 256, 0, stream>>>(x, Wqh, Wql, bqkv, Qc, Kc, Vh, Vl);
  // 3) correlation partials (P overwrites Wq splits - dead after GEMM1)
  corr_partial<<<dim3(64, 16), 256, 0, stream>>>(Qc, Kc, P);
  // 4) finalize corr
  corr_finalize<<<dim3(64, 4), 256, 0, stream>>>(P, corrB);
  // 5) Weff_b = fold(corr_b, Wout) -> bf16 hi/lo directly (split fused)
  weff_kernel<<<dim3(64, 8), 256, 0, stream>>>(corrB, Wout, Weh, Wel);
  // 6) out = v @ Weff_b^T + bout (batched over b; 2048 blocks)
  gemm2_mfma<<<dim3(8, 64, 4), 256, 0, stream>>>(Vh, Vl, Weh, Wel, bout, out);
}